// Round 12
// baseline (780.220 us; speedup 1.0000x reference)
//
#include <hip/hip_runtime.h>
#include <math.h>
#include <stdint.h>

typedef _Float16 half_t;
typedef _Float16 half8 __attribute__((ext_vector_type(8)));
typedef __fp16 fp16x2 __attribute__((ext_vector_type(2)));
typedef float floatx4 __attribute__((ext_vector_type(4)));
typedef float floatx16 __attribute__((ext_vector_type(16)));

constexpr float BN_EPS_C = 1e-5f;
constexpr float RES_SCALE_C = 0.70710678118654752f;
constexpr float GAMMA_C = 1.5f;
#define B_TOT 65536

// ---------------- packed (hi,lo) fp16-pair helpers ----------------
__device__ __forceinline__ uint32_t pack2(float y) {
    const half_t h = (half_t)y;
    const half_t l = (half_t)(y - (float)h);
    union { half_t f; unsigned short u; } a, b; a.f = h; b.f = l;
    return (uint32_t)a.u | ((uint32_t)b.u << 16);
}
__device__ __forceinline__ void unpack2(uint32_t v, half_t& h, half_t& l) {
    union { unsigned short u; half_t f; } a, b;
    a.u = (unsigned short)(v & 0xffffu); b.u = (unsigned short)(v >> 16);
    h = a.f; l = b.f;
}
__device__ __forceinline__ void split_pair(float y0, float y1, half_t& h0, half_t& l0, half_t& h1, half_t& l1) {
    fp16x2 hh = __builtin_amdgcn_cvt_pkrtz(y0, y1);
    fp16x2 ll = __builtin_amdgcn_cvt_pkrtz(y0 - (float)hh.x, y1 - (float)hh.y);
    h0 = (half_t)hh.x; l0 = (half_t)ll.x; h1 = (half_t)hh.y; l1 = (half_t)ll.y;
}
__device__ __forceinline__ void pack2_pair(float y0, float y1, uint32_t& w0, uint32_t& w1) {
    fp16x2 hh = __builtin_amdgcn_cvt_pkrtz(y0, y1);
    fp16x2 ll = __builtin_amdgcn_cvt_pkrtz(y0 - (float)hh.x, y1 - (float)hh.y);
    const uint32_t hb = __builtin_bit_cast(uint32_t, hh);
    const uint32_t lb = __builtin_bit_cast(uint32_t, ll);
    w0 = (hb & 0xffffu) | (lb << 16);
    w1 = (hb >> 16) | (lb & 0xffff0000u);
}
__device__ __forceinline__ void unpack8(const uint32_t* wv, half8& h, half8& l) {
#pragma unroll
    for (int j = 0; j < 8; ++j) {
        half_t hh, ll; unpack2(wv[j], hh, ll);
        h[j] = hh; l[j] = ll;
    }
}

// ---------------- W split+repack (fragment-major, hi/lo planes) ----------------
// RES_SCALE folded into L3/L4 weights (their inputs are stored unscaled).
__global__ void wsplit_kernel(const float* __restrict__ sh_W0, const float* __restrict__ sh_W1,
                              const float* __restrict__ init_W, const float* __restrict__ step_W,
                              half_t* __restrict__ Wh, half_t* __restrict__ Wl)
{
    const int b = blockIdx.x, n = threadIdx.x;
    const float* src; int k; size_t base;
    if (b < 320)      { src = sh_W0;           k = b;       base = 0; }
    else if (b < 448) { src = sh_W1;           k = b - 320; base = 81920; }
    else if (b < 576) { src = init_W;          k = b - 448; base = 114688; }
    else if (b < 704) { src = init_W + 32768;  k = b - 576; base = 147456; }
    else {
        int j = (b - 704) >> 7; k = (b - 704) & 127;
        src = step_W + (size_t)j * 32768; base = 180224 + (size_t)j * 32768;
    }
    float v = src[k * 256 + n];
    if (b >= 448) v *= RES_SCALE_C;
    const half_t hi = (half_t)v;
    const half_t lo = (half_t)(v - (float)hi);
    const size_t idx = base + (size_t)(((k >> 3) * 256 + n) * 8 + (k & 7));
    Wh[idx] = hi; Wl[idx] = lo;
}

__global__ void wsplit_att_kernel(const float* __restrict__ att_W,
                                  half_t* __restrict__ aWh, half_t* __restrict__ aWl)
{
    const int b = blockIdx.x;
    const int n = threadIdx.x;
    const int step = b >> 6, k = b & 63;
    const float v = att_W[(size_t)b * 80 + n] * RES_SCALE_C;   // a is stored unscaled
    const half_t h = (half_t)v;
    const half_t l = (half_t)(v - (float)h);
    const size_t idx = (size_t)step * 5120 + (size_t)(((k >> 3) * 80 + n) * 8 + (k & 7));
    aWh[idx] = h; aWl[idx] = l;
}

__global__ void embed_bn_kernel(const float* __restrict__ x_num, const int* __restrict__ x_cat,
                                const float* __restrict__ emb_W, const float* __restrict__ in_bn,
                                uint32_t* __restrict__ xp)
{
    const int idx = blockIdx.x * 256 + threadIdx.x;
    const int s = idx / 320, j = idx - s * 320;
    float v;
    if (j < 64) v = x_num[(size_t)s * 64 + j];
    else {
        const int c = (j - 64) >> 4, e = (j - 64) & 15;
        v = emb_W[(size_t)(c * 1000 + x_cat[(size_t)s * 16 + c]) * 16 + e];
    }
    const float val = (v - in_bn[640 + j]) * (in_bn[j] * __frsqrt_rn(in_bn[960 + j] + BN_EPS_C)) + in_bn[320 + j];
    xp[idx] = pack2(val);
}

__device__ __forceinline__ void bn_fold(const float* __restrict__ bn, const float* __restrict__ bias,
                                        int c, float& sc, float& sh)
{
    sc = bn[c] * __frsqrt_rn(bn[768 + c] + BN_EPS_C);
    sh = fmaf(bias[c] - bn[512 + c], sc, bn[256 + c]);
}

__device__ __forceinline__ float glu_val(float accO, float accG,
                                         float sc_o, float sh_o, float sc_g, float sh_g)
{
    const float o = fmaf(accO, sc_o, sh_o);
    const float g = fmaf(accG, sc_g, sh_g);
    const float e = __expf(-g);
    return o * __builtin_amdgcn_rcpf(1.f + e);
}

#define MFMA32(A, B, C) C = __builtin_amdgcn_mfma_f32_32x32x16_f16(A, B, C, 0, 0, 0)
#define MFMA16(A, B, C) C = __builtin_amdgcn_mfma_f32_16x16x32_f16(A, B, C, 0, 0, 0)

// K=128 layer accumulate from split-plane H (8 slices of 16-k, rotated start); wave owns 2 m-tiles.
__device__ __forceinline__ void layer_accum(const half_t (*H_h)[136], const half_t (*H_l)[136],
                                            const half_t* __restrict__ Wh, const half_t* __restrict__ Wl,
                                            size_t off, int n32, int k8, int no, int m0, int rot,
                                            floatx16* accO, floatx16* accG)
{
#pragma unroll 2
    for (int s = 0; s < 8; ++s) {
        const int sl8 = (s + rot) & 7;
        const int kq = sl8 * 2 + k8;
        const size_t wo = off + (size_t)(kq * 256 + no + n32) * 8;
        const half8 bo_h = *(const half8*)(Wh + wo);
        const half8 bo_l = *(const half8*)(Wl + wo);
        const half8 bg_h = *(const half8*)(Wh + wo + 1024);
        const half8 bg_l = *(const half8*)(Wl + wo + 1024);
#pragma unroll
        for (int mt = 0; mt < 2; ++mt) {
            const half8 a_h = *(const half8*)&H_h[m0 + mt * 32 + n32][sl8 * 16 + k8 * 8];
            const half8 a_l = *(const half8*)&H_l[m0 + mt * 32 + n32][sl8 * 16 + k8 * 8];
            MFMA32(a_h, bo_h, accO[mt]); MFMA32(a_h, bg_h, accG[mt]);
            MFMA32(a_l, bo_h, accO[mt]); MFMA32(a_l, bg_h, accG[mt]);
            MFMA32(a_h, bo_l, accO[mt]); MFMA32(a_h, bg_l, accG[mt]);
        }
    }
}

// ---------------- fused (att+sparsemax) + FT chain, 128 samples/block, 512 threads / 8 waves ----------------
template<bool MASK>
__global__ __launch_bounds__(512, 4)
void ft_chain(const uint32_t* __restrict__ xp, uint32_t* __restrict__ avp,
              const half_t* __restrict__ Wh, const half_t* __restrict__ Wl,
              const half_t* __restrict__ aWh, const half_t* __restrict__ aWl,
              const float* __restrict__ att_b, const float* __restrict__ att_bn,
              float* __restrict__ prior,
              const float* __restrict__ b1, const float* __restrict__ bn1,
              const float* __restrict__ b2, const float* __restrict__ bn2,
              const float* __restrict__ b3, const float* __restrict__ bn3,
              const float* __restrict__ b4, const float* __restrict__ bn4,
              size_t w3_off, size_t w4_off,
              float* __restrict__ ds, int wmode_last, int step)
{
    // LDS overlay (79872 B):
    //  mgs float[128][84]           [0,43008)         live: att -> end of L1 staging
    //  Apk uint32[128][68]          [43008,77824)     live: att stage only
    //  As  uint32[2][128][36]       [43008,79872)     live: L1 (double-buffered chunk tiles)
    //  H   half planes [128][136]x2 [0,69632)         live: after L1 epilogue
    __shared__ __align__(16) char smem[79872];
    float    (*mgs)[84]  = (float    (*)[84])smem;
    uint32_t (*Apk)[68]  = (uint32_t (*)[68])(smem + 43008);
    uint32_t (*As0)[36]  = (uint32_t (*)[36])(smem + 43008);
    uint32_t (*As1)[36]  = (uint32_t (*)[36])(smem + 61440);
    half_t   (*H_h)[136] = (half_t   (*)[136])smem;
    half_t   (*H_l)[136] = (half_t   (*)[136])(smem + 34816);

    const int t = threadIdx.x;
    const int s0 = blockIdx.x * 128;
    const int w = t >> 6, lane = t & 63;
    const int wq = w & 3, wh = w >> 2;
    const int n32 = lane & 31, k8 = lane >> 5;
    const int quad = lane >> 4, l16 = lane & 15;
    const int no = 32 * wq;
    const int m0 = wh * 64;
    const int half_id = (blockIdx.x >> 8) & 1;
    const int rowA = t >> 2, kA8 = (t & 3) * 8;   // L1 staging: 8 words/thread/chunk

    if (MASK) {
        {   // stage avp -> Apk (16 words/thread)
            const int kA16 = (t & 3) * 16;
            const uint4* src = (const uint4*)(avp + (size_t)(s0 + rowA) * 64 + kA16);
            uint4* dst = (uint4*)&Apk[rowA][kA16];
#pragma unroll
            for (int q = 0; q < 4; ++q) dst[q] = src[q];
        }
        __syncthreads();
        // z = BN(a@attW + b) * prior  (wave w owns m-tile w)
        floatx4 zacc[5];
#pragma unroll
        for (int nt = 0; nt < 5; ++nt) zacc[nt] = (floatx4){0.f, 0.f, 0.f, 0.f};
#pragma unroll
        for (int kc = 0; kc < 64; kc += 32) {
            uint32_t wv[8];
            *(uint4*)&wv[0] = *(const uint4*)&Apk[w * 16 + l16][kc + quad * 8];
            *(uint4*)&wv[4] = *(const uint4*)&Apk[w * 16 + l16][kc + quad * 8 + 4];
            half8 a_h, a_l;
            unpack8(wv, a_h, a_l);
            const int kq = (kc >> 3) + quad;
#pragma unroll
            for (int nt = 0; nt < 5; ++nt) {
                const size_t wi = (size_t)(kq * 80 + nt * 16 + l16) * 8;
                const half8 b_h = *(const half8*)(aWh + wi);
                const half8 b_l = *(const half8*)(aWl + wi);
                MFMA16(a_h, b_h, zacc[nt]);
                MFMA16(a_l, b_h, zacc[nt]);
                MFMA16(a_h, b_l, zacc[nt]);
            }
        }
        float preg[5][4];
#pragma unroll
        for (int nt = 0; nt < 5; ++nt) {
            const int c = nt * 16 + l16;
            const float sc = att_bn[c] * __frsqrt_rn(att_bn[240 + c] + BN_EPS_C);
            const float sh = fmaf(att_b[c] - att_bn[160 + c], sc, att_bn[80 + c]);
#pragma unroll
            for (int r = 0; r < 4; ++r) {
                const int sl = w * 16 + quad * 4 + r;
                const float pr = (step == 0) ? 1.f : prior[(size_t)(s0 + sl) * 80 + c];
                preg[nt][r] = pr;
                mgs[sl][c] = fmaf(zacc[nt][r], sc, sh) * pr;
            }
        }
        __syncthreads();
        // bisection sparsemax: 4 threads/sample, 20 groups each
        {
            const int samp = rowA, j0 = (t & 3) * 20;
            float zj[20], zmax = -1e30f;
#pragma unroll
            for (int j = 0; j < 20; ++j) { zj[j] = mgs[samp][j0 + j]; zmax = fmaxf(zmax, zj[j]); }
            zmax = fmaxf(zmax, __shfl_xor(zmax, 1));
            zmax = fmaxf(zmax, __shfl_xor(zmax, 2));
            float lo = zmax - 1.f, hi = zmax;
#pragma unroll 1
            for (int it = 0; it < 16; ++it) {
                const float mid = 0.5f * (lo + hi);
                float ssum = 0.f;
#pragma unroll
                for (int j = 0; j < 20; ++j) ssum += fmaxf(zj[j] - mid, 0.f);
                ssum += __shfl_xor(ssum, 1);
                ssum += __shfl_xor(ssum, 2);
                if (ssum >= 1.f) lo = mid; else hi = mid;
            }
            const float tau = 0.5f * (lo + hi);
#pragma unroll
            for (int j = 0; j < 20; ++j) mgs[samp][j0 + j] = fmaxf(zj[j] - tau, 0.f);
        }
        __syncthreads();
        // prior update
#pragma unroll
        for (int nt = 0; nt < 5; ++nt) {
            const int c = nt * 16 + l16;
#pragma unroll
            for (int r = 0; r < 4; ++r) {
                const int sl = w * 16 + quad * 4 + r;
                prior[(size_t)(s0 + sl) * 80 + c] = preg[nt][r] * (GAMMA_C - mgs[sl][c]);
            }
        }
    }

    // ---------------- L1: K=320 as 10 chunks of 32, double-buffered As, staging interleaved with MFMA
    floatx16 accO[2], accG[2];
#pragma unroll
    for (int i = 0; i < 2; ++i) { accO[i] = (floatx16)(0.f); accG[i] = (floatx16)(0.f); }

    const uint32_t* arow = xp + (size_t)(s0 + rowA) * 320 + kA8;
    uint32_t pfw[2][8];
    const int ic0 = half_id * 5;

    // stage-half helper as a lambda: chunk c, half sl2, dest buffer
    auto stage_half = [&](uint32_t (*Asb)[36], int c, int sl2, const uint32_t* pf) {
        const int kb = c * 32 + kA8 + sl2 * 4;   // 4 features
        uint4 out;
        if (MASK) {
            float m[4];
            if (c < 2) {
                const float4 mq = *(const float4*)&mgs[rowA][kb];
                m[0] = mq.x; m[1] = mq.y; m[2] = mq.z; m[3] = mq.w;
            } else {
                const float mg = mgs[rowA][64 + ((kb - 64) >> 4)];
                m[0] = m[1] = m[2] = m[3] = mg;
            }
            float y[4];
#pragma unroll
            for (int j = 0; j < 4; ++j) {
                half_t h, l; unpack2(pf[sl2 * 4 + j], h, l);
                y[j] = ((float)h + (float)l) * m[j];
            }
            uint32_t w0, w1, w2, w3;
            pack2_pair(y[0], y[1], w0, w1);
            pack2_pair(y[2], y[3], w2, w3);
            out = make_uint4(w0, w1, w2, w3);
        } else {
            out = *(const uint4*)&pf[sl2 * 4];
        }
        *(uint4*)&Asb[rowA][kA8 + sl2 * 4] = out;
    };

    // prologue: load chunk c0 -> pfw[0], stage As0, load chunk c1 -> pfw[1]
    {
        *(uint4*)&pfw[0][0] = *(const uint4*)(arow + ic0 * 32);
        *(uint4*)&pfw[0][4] = *(const uint4*)(arow + ic0 * 32 + 4);
        stage_half(As0, ic0, 0, pfw[0]);
        stage_half(As0, ic0, 1, pfw[0]);
        const int c1 = (ic0 + 1) % 10;
        *(uint4*)&pfw[1][0] = *(const uint4*)(arow + c1 * 32);
        *(uint4*)&pfw[1][4] = *(const uint4*)(arow + c1 * 32 + 4);
    }
    __syncthreads();

#pragma unroll 1
    for (int i = 0; i < 10; ++i) {
        const int cc = (ic0 + i) % 10;
        const int cn = (cc + 1 == 10) ? 0 : cc + 1;
        uint32_t (*AsC)[36] = (i & 1) ? As1 : As0;
        uint32_t (*AsN)[36] = (i & 1) ? As0 : As1;
        if (i <= 7) {   // prefetch chunk i+2 into slot i&1 (consumed at iter i+1's staging)
            const int c2 = (ic0 + i + 2) % 10;
            *(uint4*)&pfw[i & 1][0] = *(const uint4*)(arow + c2 * 32);
            *(uint4*)&pfw[i & 1][4] = *(const uint4*)(arow + c2 * 32 + 4);
        }
#pragma unroll
        for (int sl4 = 0; sl4 < 2; ++sl4) {
            if (i < 9) stage_half(AsN, cn, sl4, pfw[(i + 1) & 1]);
            // MFMA slice sl4 of chunk cc from AsC
            const int kq = cc * 4 + sl4 * 2 + k8;
            const size_t wo = (size_t)(kq * 256 + no + n32) * 8;
            const half8 bo_h = *(const half8*)(Wh + wo);
            const half8 bo_l = *(const half8*)(Wl + wo);
            const half8 bg_h = *(const half8*)(Wh + wo + 1024);
            const half8 bg_l = *(const half8*)(Wl + wo + 1024);
#pragma unroll
            for (int mt = 0; mt < 2; ++mt) {
                uint32_t wv[8];
                *(uint4*)&wv[0] = *(const uint4*)&AsC[m0 + mt * 32 + n32][sl4 * 16 + k8 * 8];
                *(uint4*)&wv[4] = *(const uint4*)&AsC[m0 + mt * 32 + n32][sl4 * 16 + k8 * 8 + 4];
                half8 a_h, a_l;
                unpack8(wv, a_h, a_l);
                MFMA32(a_h, bo_h, accO[mt]); MFMA32(a_h, bg_h, accG[mt]);
                MFMA32(a_l, bo_h, accO[mt]); MFMA32(a_l, bg_h, accG[mt]);
                MFMA32(a_h, bo_l, accO[mt]); MFMA32(a_h, bg_l, accG[mt]);
            }
        }
        __syncthreads();
    }

    // L1 epilogue -> H planes (u1 = g1, no residual)
    {
        const int c = no + n32;
        float sc_o, sh_o, sc_g, sh_g;
        bn_fold(bn1, b1, c, sc_o, sh_o);
        bn_fold(bn1, b1, c + 128, sc_g, sh_g);
#pragma unroll
        for (int mt = 0; mt < 2; ++mt)
#pragma unroll
            for (int q = 0; q < 4; ++q)
#pragma unroll
                for (int rp = 0; rp < 2; ++rp) {
                    const int r0 = q * 4 + rp * 2;
                    const int sl = m0 + mt * 32 + rp * 2 + 8 * q + 4 * k8;
                    const float y0 = glu_val(accO[mt][r0],     accG[mt][r0],     sc_o, sh_o, sc_g, sh_g);
                    const float y1 = glu_val(accO[mt][r0 + 1], accG[mt][r0 + 1], sc_o, sh_o, sc_g, sh_g);
                    half_t h0, l0, h1, l1;
                    split_pair(y0, y1, h0, l0, h1, l1);
                    H_h[sl][c] = h0; H_l[sl][c] = l0;
                    H_h[sl + 1][c] = h1; H_l[sl + 1][c] = l1;
                }
    }
    __syncthreads();

    // ---------------- L2, L3 (scale folded: L2 u=g+res; L3 u=fma(s,res,g))
#pragma unroll 1
    for (int layer = 0; layer < 2; ++layer) {
        const float* bb = layer ? b3 : b2;
        const float* bn = layer ? bn3 : bn2;
        const size_t off = layer ? w3_off : (size_t)81920;
        const float rs = layer ? RES_SCALE_C : 1.0f;
#pragma unroll
        for (int i = 0; i < 2; ++i) { accO[i] = (floatx16)(0.f); accG[i] = (floatx16)(0.f); }
        layer_accum(H_h, H_l, Wh, Wl, off, n32, k8, no, m0, half_id * 4, accO, accG);
        __syncthreads();
        {
            const int c = no + n32;
            float sc_o, sh_o, sc_g, sh_g;
            bn_fold(bn, bb, c, sc_o, sh_o);
            bn_fold(bn, bb, c + 128, sc_g, sh_g);
#pragma unroll
            for (int mt = 0; mt < 2; ++mt)
#pragma unroll
                for (int q = 0; q < 4; ++q)
#pragma unroll
                    for (int rp = 0; rp < 2; ++rp) {
                        const int r0 = q * 4 + rp * 2;
                        const int sl = m0 + mt * 32 + rp * 2 + 8 * q + 4 * k8;
                        const float res0 = (float)H_h[sl][c] + (float)H_l[sl][c];
                        const float res1 = (float)H_h[sl + 1][c] + (float)H_l[sl + 1][c];
                        const float y0 = fmaf(rs, res0, glu_val(accO[mt][r0],     accG[mt][r0],     sc_o, sh_o, sc_g, sh_g));
                        const float y1 = fmaf(rs, res1, glu_val(accO[mt][r0 + 1], accG[mt][r0 + 1], sc_o, sh_o, sc_g, sh_g));
                        half_t h0, l0, h1, l1;
                        split_pair(y0, y1, h0, l0, h1, l1);
                        H_h[sl][c] = h0; H_l[sl][c] = l0;
                        H_h[sl + 1][c] = h1; H_l[sl + 1][c] = l1;
                    }
        }
        __syncthreads();
    }

    // ---------------- L4 -> global outputs (u4 = fma(s, res, g4); outputs stored unscaled)
#pragma unroll
    for (int i = 0; i < 2; ++i) { accO[i] = (floatx16)(0.f); accG[i] = (floatx16)(0.f); }
    layer_accum(H_h, H_l, Wh, Wl, w4_off, n32, k8, no, m0, half_id * 4, accO, accG);
    {
        const int c = no + n32;
        float sc_o, sh_o, sc_g, sh_g;
        bn_fold(bn4, b4, c, sc_o, sh_o);
        bn_fold(bn4, b4, c + 128, sc_g, sh_g);
        if (wq < 2) {
            if (wmode_last != 1) {
#pragma unroll
                for (int mt = 0; mt < 2; ++mt)
#pragma unroll
                    for (int reg = 0; reg < 16; ++reg) {
                        const int sl = m0 + mt * 32 + (reg & 3) + 8 * (reg >> 2) + 4 * k8;
                        const float res = (float)H_h[sl][c] + (float)H_l[sl][c];
                        const float y = fmaf(RES_SCALE_C, res, glu_val(accO[mt][reg], accG[mt][reg], sc_o, sh_o, sc_g, sh_g));
                        const float d = fmaxf(y, 0.f);
                        float* dp = ds + (size_t)(s0 + sl) * 64 + c;
                        *dp = (wmode_last == 2) ? d : (*dp + d);
                    }
            }
        } else {
#pragma unroll
            for (int mt = 0; mt < 2; ++mt)
#pragma unroll
                for (int q = 0; q < 4; ++q)
#pragma unroll
                    for (int rp = 0; rp < 2; ++rp) {
                        const int r0 = q * 4 + rp * 2;
                        const int sl = m0 + mt * 32 + rp * 2 + 8 * q + 4 * k8;
                        const float res0 = (float)H_h[sl][c] + (float)H_l[sl][c];
                        const float res1 = (float)H_h[sl + 1][c] + (float)H_l[sl + 1][c];
                        const float y0 = fmaf(RES_SCALE_C, res0, glu_val(accO[mt][r0],     accG[mt][r0],     sc_o, sh_o, sc_g, sh_g));
                        const float y1 = fmaf(RES_SCALE_C, res1, glu_val(accO[mt][r0 + 1], accG[mt][r0 + 1], sc_o, sh_o, sc_g, sh_g));
                        uint32_t w0, w1;
                        pack2_pair(y0, y1, w0, w1);
                        avp[(size_t)(s0 + sl) * 64 + (c - 64)] = w0;
                        avp[(size_t)(s0 + sl + 1) * 64 + (c - 64)] = w1;
                    }
        }
    }
}

// ---------------- final 64 -> 1 (RES_SCALE applied here: ds holds unscaled relu) ----------------
__global__ void final_kernel(const float* __restrict__ dsum, const float* __restrict__ out_W,
                             const float* __restrict__ out_b, float* __restrict__ out)
{
    const int s = blockIdx.x * 256 + threadIdx.x;
    float acc = 0.f;
    const float4* dp = (const float4*)(dsum + (size_t)s * 64);
    const float4* wp = (const float4*)out_W;
#pragma unroll
    for (int q = 0; q < 16; ++q) {
        const float4 d = dp[q];
        const float4 ww = wp[q];
        acc += d.x * ww.x + d.y * ww.y + d.z * ww.z + d.w * ww.w;
    }
    out[s] = fmaf(RES_SCALE_C, acc, out_b[0]);
}

// ---------------- launch ----------------
extern "C" void kernel_launch(void* const* d_in, const int* in_sizes, int n_in,
                              void* d_out, int out_size, void* d_ws, size_t ws_size,
                              hipStream_t stream)
{
    const float* x_num  = (const float*)d_in[0];
    const int*   x_cat  = (const int*)d_in[1];
    const float* emb_W  = (const float*)d_in[2];
    const float* in_bn  = (const float*)d_in[3];
    const float* sh_W0  = (const float*)d_in[4];
    const float* sh_b0  = (const float*)d_in[5];
    const float* sh_bn0 = (const float*)d_in[6];
    const float* sh_W1  = (const float*)d_in[7];
    const float* sh_b1  = (const float*)d_in[8];
    const float* sh_bn1 = (const float*)d_in[9];
    const float* init_W = (const float*)d_in[10];
    const float* init_b = (const float*)d_in[11];
    const float* init_bn= (const float*)d_in[12];
    const float* step_W = (const float*)d_in[13];
    const float* step_b = (const float*)d_in[14];
    const float* step_bn= (const float*)d_in[15];
    const float* att_W  = (const float*)d_in[16];
    const float* att_b  = (const float*)d_in[17];
    const float* att_bn = (const float*)d_in[18];
    const float* out_W  = (const float*)d_in[19];
    const float* out_b  = (const float*)d_in[20];

    const size_t B = B_TOT;
    char* p = (char*)d_ws;
    uint32_t* xp  = (uint32_t*)p;  p += B * 320 * 4;
    uint32_t* avp = (uint32_t*)p;  p += B * 64 * 4;
    half_t* Wh    = (half_t*)p;    p += 507904 * 2;
    half_t* Wl    = (half_t*)p;    p += 507904 * 2;
    half_t* aWh   = (half_t*)p;    p += 25600 * 2;
    half_t* aWl   = (half_t*)p;    p += 25600 * 2;
    float* pri    = (float*)p;     p += B * 80 * 4;
    float* ds     = (float*)p;     p += B * 64 * 4;

    wsplit_kernel<<<1984, 256, 0, stream>>>(sh_W0, sh_W1, init_W, step_W, Wh, Wl);
    wsplit_att_kernel<<<320, 80, 0, stream>>>(att_W, aWh, aWl);
    embed_bn_kernel<<<(B_TOT * 320) / 256, 256, 0, stream>>>(x_num, x_cat, emb_W, in_bn, xp);

    const int GB = B_TOT / 128;   // 512 blocks
    ft_chain<false><<<GB, 512, 0, stream>>>(xp, avp, Wh, Wl,
                                            nullptr, nullptr, nullptr, nullptr, nullptr,
                                            sh_b0, sh_bn0, sh_b1, sh_bn1,
                                            init_b, init_bn, init_b + 256, init_bn + 1024,
                                            (size_t)114688, (size_t)147456, ds, 1, 0);
    for (int st = 0; st < 5; ++st) {
        const size_t w3 = 180224 + (size_t)(st * 2 + 0) * 32768;
        const size_t w4 = 180224 + (size_t)(st * 2 + 1) * 32768;
        ft_chain<true><<<GB, 512, 0, stream>>>(xp, avp, Wh, Wl,
                                               aWh + st * 5120, aWl + st * 5120,
                                               att_b + st * 80, att_bn + st * 320, pri,
                                               sh_b0, sh_bn0, sh_b1, sh_bn1,
                                               step_b + (st * 2 + 0) * 256, step_bn + (st * 2 + 0) * 1024,
                                               step_b + (st * 2 + 1) * 256, step_bn + (st * 2 + 1) * 1024,
                                               w3, w4, ds, st == 0 ? 2 : 3, st);
    }
    final_kernel<<<B_TOT / 256, 256, 0, stream>>>(ds, out_W, out_b, (float*)d_out);
}

// Round 13
// 701.587 us; speedup vs baseline: 1.1121x; 1.1121x over previous
//
#include <hip/hip_runtime.h>
#include <math.h>
#include <stdint.h>

typedef _Float16 half_t;
typedef _Float16 half8 __attribute__((ext_vector_type(8)));
typedef __fp16 fp16x2 __attribute__((ext_vector_type(2)));
typedef float floatx4 __attribute__((ext_vector_type(4)));
typedef float floatx16 __attribute__((ext_vector_type(16)));

constexpr float BN_EPS_C = 1e-5f;
constexpr float RES_SCALE_C = 0.70710678118654752f;
constexpr float GAMMA_C = 1.5f;
#define B_TOT 65536

// ---------------- packed (hi,lo) fp16-pair helpers ----------------
__device__ __forceinline__ uint32_t pack2(float y) {
    const half_t h = (half_t)y;
    const half_t l = (half_t)(y - (float)h);
    union { half_t f; unsigned short u; } a, b; a.f = h; b.f = l;
    return (uint32_t)a.u | ((uint32_t)b.u << 16);
}
__device__ __forceinline__ void unpack2(uint32_t v, half_t& h, half_t& l) {
    union { unsigned short u; half_t f; } a, b;
    a.u = (unsigned short)(v & 0xffffu); b.u = (unsigned short)(v >> 16);
    h = a.f; l = b.f;
}
__device__ __forceinline__ void split_pair(float y0, float y1, half_t& h0, half_t& l0, half_t& h1, half_t& l1) {
    fp16x2 hh = __builtin_amdgcn_cvt_pkrtz(y0, y1);
    fp16x2 ll = __builtin_amdgcn_cvt_pkrtz(y0 - (float)hh.x, y1 - (float)hh.y);
    h0 = (half_t)hh.x; l0 = (half_t)ll.x; h1 = (half_t)hh.y; l1 = (half_t)ll.y;
}
__device__ __forceinline__ void pack2_pair(float y0, float y1, uint32_t& w0, uint32_t& w1) {
    fp16x2 hh = __builtin_amdgcn_cvt_pkrtz(y0, y1);
    fp16x2 ll = __builtin_amdgcn_cvt_pkrtz(y0 - (float)hh.x, y1 - (float)hh.y);
    const uint32_t hb = __builtin_bit_cast(uint32_t, hh);
    const uint32_t lb = __builtin_bit_cast(uint32_t, ll);
    w0 = (hb & 0xffffu) | (lb << 16);
    w1 = (hb >> 16) | (lb & 0xffff0000u);
}
__device__ __forceinline__ void unpack8(const uint32_t* wv, half8& h, half8& l) {
#pragma unroll
    for (int j = 0; j < 8; ++j) {
        half_t hh, ll; unpack2(wv[j], hh, ll);
        h[j] = hh; l[j] = ll;
    }
}

// ---------------- W split+repack (fragment-major, hi/lo planes) ----------------
// RES_SCALE folded into L3/L4 weights (their inputs are stored unscaled).
__global__ void wsplit_kernel(const float* __restrict__ sh_W0, const float* __restrict__ sh_W1,
                              const float* __restrict__ init_W, const float* __restrict__ step_W,
                              half_t* __restrict__ Wh, half_t* __restrict__ Wl)
{
    const int b = blockIdx.x, n = threadIdx.x;
    const float* src; int k; size_t base;
    if (b < 320)      { src = sh_W0;           k = b;       base = 0; }
    else if (b < 448) { src = sh_W1;           k = b - 320; base = 81920; }
    else if (b < 576) { src = init_W;          k = b - 448; base = 114688; }
    else if (b < 704) { src = init_W + 32768;  k = b - 576; base = 147456; }
    else {
        int j = (b - 704) >> 7; k = (b - 704) & 127;
        src = step_W + (size_t)j * 32768; base = 180224 + (size_t)j * 32768;
    }
    float v = src[k * 256 + n];
    if (b >= 448) v *= RES_SCALE_C;
    const half_t hi = (half_t)v;
    const half_t lo = (half_t)(v - (float)hi);
    const size_t idx = base + (size_t)(((k >> 3) * 256 + n) * 8 + (k & 7));
    Wh[idx] = hi; Wl[idx] = lo;
}

__global__ void wsplit_att_kernel(const float* __restrict__ att_W,
                                  half_t* __restrict__ aWh, half_t* __restrict__ aWl)
{
    const int b = blockIdx.x;
    const int n = threadIdx.x;
    const int step = b >> 6, k = b & 63;
    const float v = att_W[(size_t)b * 80 + n] * RES_SCALE_C;   // a is stored unscaled
    const half_t h = (half_t)v;
    const half_t l = (half_t)(v - (float)h);
    const size_t idx = (size_t)step * 5120 + (size_t)(((k >> 3) * 80 + n) * 8 + (k & 7));
    aWh[idx] = h; aWl[idx] = l;
}

__global__ void embed_bn_kernel(const float* __restrict__ x_num, const int* __restrict__ x_cat,
                                const float* __restrict__ emb_W, const float* __restrict__ in_bn,
                                uint32_t* __restrict__ xp)
{
    const int idx = blockIdx.x * 256 + threadIdx.x;
    const int s = idx / 320, j = idx - s * 320;
    float v;
    if (j < 64) v = x_num[(size_t)s * 64 + j];
    else {
        const int c = (j - 64) >> 4, e = (j - 64) & 15;
        v = emb_W[(size_t)(c * 1000 + x_cat[(size_t)s * 16 + c]) * 16 + e];
    }
    const float val = (v - in_bn[640 + j]) * (in_bn[j] * __frsqrt_rn(in_bn[960 + j] + BN_EPS_C)) + in_bn[320 + j];
    xp[idx] = pack2(val);
}

__device__ __forceinline__ void bn_fold(const float* __restrict__ bn, const float* __restrict__ bias,
                                        int c, float& sc, float& sh)
{
    sc = bn[c] * __frsqrt_rn(bn[768 + c] + BN_EPS_C);
    sh = fmaf(bias[c] - bn[512 + c], sc, bn[256 + c]);
}

__device__ __forceinline__ float glu_val(float accO, float accG,
                                         float sc_o, float sh_o, float sc_g, float sh_g)
{
    const float o = fmaf(accO, sc_o, sh_o);
    const float g = fmaf(accG, sc_g, sh_g);
    const float e = __expf(-g);
    return o * __builtin_amdgcn_rcpf(1.f + e);
}

#define MFMA32(A, B, C) C = __builtin_amdgcn_mfma_f32_32x32x16_f16(A, B, C, 0, 0, 0)
#define MFMA16(A, B, C) C = __builtin_amdgcn_mfma_f32_16x16x32_f16(A, B, C, 0, 0, 0)

// K=128 layer accumulate from split-plane H (8 slices of 16-k, rotated start); wave owns 2 m-tiles.
__device__ __forceinline__ void layer_accum(const half_t (*H_h)[136], const half_t (*H_l)[136],
                                            const half_t* __restrict__ Wh, const half_t* __restrict__ Wl,
                                            size_t off, int n32, int k8, int no, int m0, int rot,
                                            floatx16* accO, floatx16* accG)
{
#pragma unroll 2
    for (int s = 0; s < 8; ++s) {
        const int sl8 = (s + rot) & 7;
        const int kq = sl8 * 2 + k8;
        const size_t wo = off + (size_t)(kq * 256 + no + n32) * 8;
        const half8 bo_h = *(const half8*)(Wh + wo);
        const half8 bo_l = *(const half8*)(Wl + wo);
        const half8 bg_h = *(const half8*)(Wh + wo + 1024);
        const half8 bg_l = *(const half8*)(Wl + wo + 1024);
#pragma unroll
        for (int mt = 0; mt < 2; ++mt) {
            const half8 a_h = *(const half8*)&H_h[m0 + mt * 32 + n32][sl8 * 16 + k8 * 8];
            const half8 a_l = *(const half8*)&H_l[m0 + mt * 32 + n32][sl8 * 16 + k8 * 8];
            MFMA32(a_h, bo_h, accO[mt]); MFMA32(a_h, bg_h, accG[mt]);
            MFMA32(a_l, bo_h, accO[mt]); MFMA32(a_l, bg_h, accG[mt]);
            MFMA32(a_h, bo_l, accO[mt]); MFMA32(a_h, bg_l, accG[mt]);
        }
    }
}

// ---------------- fused (att+sparsemax) + FT chain, 128 samples/block, 512 threads / 8 waves ----------------
template<bool MASK>
__global__ __launch_bounds__(512, 4)
void ft_chain(const uint32_t* __restrict__ xp, uint32_t* __restrict__ avp,
              const half_t* __restrict__ Wh, const half_t* __restrict__ Wl,
              const half_t* __restrict__ aWh, const half_t* __restrict__ aWl,
              const float* __restrict__ att_b, const float* __restrict__ att_bn,
              float* __restrict__ prior,
              const float* __restrict__ b1, const float* __restrict__ bn1,
              const float* __restrict__ b2, const float* __restrict__ bn2,
              const float* __restrict__ b3, const float* __restrict__ bn3,
              const float* __restrict__ b4, const float* __restrict__ bn4,
              size_t w3_off, size_t w4_off,
              float* __restrict__ ds, int wmode_last, int step)
{
    // LDS overlay (79872 B):
    //  mgs float[128][84]           [0,43008)         live: att -> end of L1 staging
    //  Apk uint32[128][68]          [43008,77824)     live: att stage only
    //  As  uint32[2][128][36]       [43008,79872)     live: L1 (double-buffered chunk tiles)
    //  H   half planes [128][136]x2 [0,69632)         live: after L1 epilogue
    __shared__ __align__(16) char smem[79872];
    float    (*mgs)[84]  = (float    (*)[84])smem;
    uint32_t (*Apk)[68]  = (uint32_t (*)[68])(smem + 43008);
    uint32_t (*As0)[36]  = (uint32_t (*)[36])(smem + 43008);
    uint32_t (*As1)[36]  = (uint32_t (*)[36])(smem + 61440);
    half_t   (*H_h)[136] = (half_t   (*)[136])smem;
    half_t   (*H_l)[136] = (half_t   (*)[136])(smem + 34816);

    const int t = threadIdx.x;
    const int s0 = blockIdx.x * 128;
    const int w = t >> 6, lane = t & 63;
    const int wq = w & 3, wh = w >> 2;
    const int n32 = lane & 31, k8 = lane >> 5;
    const int quad = lane >> 4, l16 = lane & 15;
    const int no = 32 * wq;
    const int m0 = wh * 64;
    const int half_id = (blockIdx.x >> 8) & 1;
    const int rowA = t >> 2, kA8 = (t & 3) * 8;   // L1 staging: 8 words/thread/chunk

    if (MASK) {
        {   // stage avp -> Apk (16 words/thread)
            const int kA16 = (t & 3) * 16;
            const uint4* src = (const uint4*)(avp + (size_t)(s0 + rowA) * 64 + kA16);
            uint4* dst = (uint4*)&Apk[rowA][kA16];
#pragma unroll
            for (int q = 0; q < 4; ++q) dst[q] = src[q];
        }
        __syncthreads();
        // z = BN(a@attW + b) * prior  (wave w owns m-tile w)
        floatx4 zacc[5];
#pragma unroll
        for (int nt = 0; nt < 5; ++nt) zacc[nt] = (floatx4){0.f, 0.f, 0.f, 0.f};
#pragma unroll
        for (int kc = 0; kc < 64; kc += 32) {
            uint32_t wv[8];
            *(uint4*)&wv[0] = *(const uint4*)&Apk[w * 16 + l16][kc + quad * 8];
            *(uint4*)&wv[4] = *(const uint4*)&Apk[w * 16 + l16][kc + quad * 8 + 4];
            half8 a_h, a_l;
            unpack8(wv, a_h, a_l);
            const int kq = (kc >> 3) + quad;
#pragma unroll
            for (int nt = 0; nt < 5; ++nt) {
                const size_t wi = (size_t)(kq * 80 + nt * 16 + l16) * 8;
                const half8 b_h = *(const half8*)(aWh + wi);
                const half8 b_l = *(const half8*)(aWl + wi);
                MFMA16(a_h, b_h, zacc[nt]);
                MFMA16(a_l, b_h, zacc[nt]);
                MFMA16(a_h, b_l, zacc[nt]);
            }
        }
        float preg[5][4];
#pragma unroll
        for (int nt = 0; nt < 5; ++nt) {
            const int c = nt * 16 + l16;
            const float sc = att_bn[c] * __frsqrt_rn(att_bn[240 + c] + BN_EPS_C);
            const float sh = fmaf(att_b[c] - att_bn[160 + c], sc, att_bn[80 + c]);
#pragma unroll
            for (int r = 0; r < 4; ++r) {
                const int sl = w * 16 + quad * 4 + r;
                const float pr = (step == 0) ? 1.f : prior[(size_t)(s0 + sl) * 80 + c];
                preg[nt][r] = pr;
                mgs[sl][c] = fmaf(zacc[nt][r], sc, sh) * pr;
            }
        }
        __syncthreads();
        // bisection sparsemax: 4 threads/sample, 20 groups each
        {
            const int samp = rowA, j0 = (t & 3) * 20;
            float zj[20], zmax = -1e30f;
#pragma unroll
            for (int j = 0; j < 20; ++j) { zj[j] = mgs[samp][j0 + j]; zmax = fmaxf(zmax, zj[j]); }
            zmax = fmaxf(zmax, __shfl_xor(zmax, 1));
            zmax = fmaxf(zmax, __shfl_xor(zmax, 2));
            float lo = zmax - 1.f, hi = zmax;
#pragma unroll 1
            for (int it = 0; it < 16; ++it) {
                const float mid = 0.5f * (lo + hi);
                float ssum = 0.f;
#pragma unroll
                for (int j = 0; j < 20; ++j) ssum += fmaxf(zj[j] - mid, 0.f);
                ssum += __shfl_xor(ssum, 1);
                ssum += __shfl_xor(ssum, 2);
                if (ssum >= 1.f) lo = mid; else hi = mid;
            }
            const float tau = 0.5f * (lo + hi);
#pragma unroll
            for (int j = 0; j < 20; ++j) mgs[samp][j0 + j] = fmaxf(zj[j] - tau, 0.f);
        }
        __syncthreads();
        // prior update
#pragma unroll
        for (int nt = 0; nt < 5; ++nt) {
            const int c = nt * 16 + l16;
#pragma unroll
            for (int r = 0; r < 4; ++r) {
                const int sl = w * 16 + quad * 4 + r;
                prior[(size_t)(s0 + sl) * 80 + c] = preg[nt][r] * (GAMMA_C - mgs[sl][c]);
            }
        }
    }

    // ---------------- L1: K=320 as 10 chunks of 32, double-buffered As, staging interleaved
    // FULLY UNROLLED so all pfw[] indices are compile-time (R12's runtime indices forced
    // scratch-backed private arrays -> +150 MB/dispatch HBM traffic).
    floatx16 accO[2], accG[2];
#pragma unroll
    for (int i = 0; i < 2; ++i) { accO[i] = (floatx16)(0.f); accG[i] = (floatx16)(0.f); }

    const uint32_t* arow = xp + (size_t)(s0 + rowA) * 320 + kA8;
    uint32_t pfw[2][8];
    const int ic0 = half_id * 5;

    auto stage_half = [&](uint32_t (*Asb)[36], int c, int sl2, const uint32_t* pf) {
        const int kb = c * 32 + kA8 + sl2 * 4;   // 4 features
        uint4 out;
        if (MASK) {
            float m[4];
            if (c < 2) {
                const float4 mq = *(const float4*)&mgs[rowA][kb];
                m[0] = mq.x; m[1] = mq.y; m[2] = mq.z; m[3] = mq.w;
            } else {
                const float mg = mgs[rowA][64 + ((kb - 64) >> 4)];
                m[0] = m[1] = m[2] = m[3] = mg;
            }
            float y[4];
#pragma unroll
            for (int j = 0; j < 4; ++j) {
                half_t h, l; unpack2(pf[sl2 * 4 + j], h, l);
                y[j] = ((float)h + (float)l) * m[j];
            }
            uint32_t w0, w1, w2, w3;
            pack2_pair(y[0], y[1], w0, w1);
            pack2_pair(y[2], y[3], w2, w3);
            out = make_uint4(w0, w1, w2, w3);
        } else {
            out = *(const uint4*)&pf[sl2 * 4];
        }
        *(uint4*)&Asb[rowA][kA8 + sl2 * 4] = out;
    };

    // prologue
    {
        *(uint4*)&pfw[0][0] = *(const uint4*)(arow + ic0 * 32);
        *(uint4*)&pfw[0][4] = *(const uint4*)(arow + ic0 * 32 + 4);
        stage_half(As0, ic0, 0, pfw[0]);
        stage_half(As0, ic0, 1, pfw[0]);
        const int c1 = (ic0 + 1) % 10;
        *(uint4*)&pfw[1][0] = *(const uint4*)(arow + c1 * 32);
        *(uint4*)&pfw[1][4] = *(const uint4*)(arow + c1 * 32 + 4);
    }
    __syncthreads();

#pragma unroll
    for (int i = 0; i < 10; ++i) {
        const int cc = (ic0 + i) % 10;
        const int cn = (cc + 1 == 10) ? 0 : cc + 1;
        uint32_t (*AsC)[36] = (i & 1) ? As1 : As0;
        uint32_t (*AsN)[36] = (i & 1) ? As0 : As1;
        if (i <= 7) {   // prefetch chunk i+2 into slot i&1 (consumed at iter i+1's staging)
            const int c2 = (ic0 + i + 2) % 10;
            *(uint4*)&pfw[i & 1][0] = *(const uint4*)(arow + c2 * 32);
            *(uint4*)&pfw[i & 1][4] = *(const uint4*)(arow + c2 * 32 + 4);
        }
#pragma unroll
        for (int sl4 = 0; sl4 < 2; ++sl4) {
            if (i < 9) stage_half(AsN, cn, sl4, pfw[(i + 1) & 1]);
            const int kq = cc * 4 + sl4 * 2 + k8;
            const size_t wo = (size_t)(kq * 256 + no + n32) * 8;
            const half8 bo_h = *(const half8*)(Wh + wo);
            const half8 bo_l = *(const half8*)(Wl + wo);
            const half8 bg_h = *(const half8*)(Wh + wo + 1024);
            const half8 bg_l = *(const half8*)(Wl + wo + 1024);
#pragma unroll
            for (int mt = 0; mt < 2; ++mt) {
                uint32_t wv[8];
                *(uint4*)&wv[0] = *(const uint4*)&AsC[m0 + mt * 32 + n32][sl4 * 16 + k8 * 8];
                *(uint4*)&wv[4] = *(const uint4*)&AsC[m0 + mt * 32 + n32][sl4 * 16 + k8 * 8 + 4];
                half8 a_h, a_l;
                unpack8(wv, a_h, a_l);
                MFMA32(a_h, bo_h, accO[mt]); MFMA32(a_h, bg_h, accG[mt]);
                MFMA32(a_l, bo_h, accO[mt]); MFMA32(a_l, bg_h, accG[mt]);
                MFMA32(a_h, bo_l, accO[mt]); MFMA32(a_h, bg_l, accG[mt]);
            }
        }
        __syncthreads();
    }

    // L1 epilogue -> H planes
    {
        const int c = no + n32;
        float sc_o, sh_o, sc_g, sh_g;
        bn_fold(bn1, b1, c, sc_o, sh_o);
        bn_fold(bn1, b1, c + 128, sc_g, sh_g);
#pragma unroll
        for (int mt = 0; mt < 2; ++mt)
#pragma unroll
            for (int q = 0; q < 4; ++q)
#pragma unroll
                for (int rp = 0; rp < 2; ++rp) {
                    const int r0 = q * 4 + rp * 2;
                    const int sl = m0 + mt * 32 + rp * 2 + 8 * q + 4 * k8;
                    const float y0 = glu_val(accO[mt][r0],     accG[mt][r0],     sc_o, sh_o, sc_g, sh_g);
                    const float y1 = glu_val(accO[mt][r0 + 1], accG[mt][r0 + 1], sc_o, sh_o, sc_g, sh_g);
                    half_t h0, l0, h1, l1;
                    split_pair(y0, y1, h0, l0, h1, l1);
                    H_h[sl][c] = h0; H_l[sl][c] = l0;
                    H_h[sl + 1][c] = h1; H_l[sl + 1][c] = l1;
                }
    }
    __syncthreads();

    // ---------------- L2, L3 (scale folded: L2 u=g+res; L3 u=fma(s,res,g))
#pragma unroll 1
    for (int layer = 0; layer < 2; ++layer) {
        const float* bb = layer ? b3 : b2;
        const float* bn = layer ? bn3 : bn2;
        const size_t off = layer ? w3_off : (size_t)81920;
        const float rs = layer ? RES_SCALE_C : 1.0f;
#pragma unroll
        for (int i = 0; i < 2; ++i) { accO[i] = (floatx16)(0.f); accG[i] = (floatx16)(0.f); }
        layer_accum(H_h, H_l, Wh, Wl, off, n32, k8, no, m0, half_id * 4, accO, accG);
        __syncthreads();
        {
            const int c = no + n32;
            float sc_o, sh_o, sc_g, sh_g;
            bn_fold(bn, bb, c, sc_o, sh_o);
            bn_fold(bn, bb, c + 128, sc_g, sh_g);
#pragma unroll
            for (int mt = 0; mt < 2; ++mt)
#pragma unroll
                for (int q = 0; q < 4; ++q)
#pragma unroll
                    for (int rp = 0; rp < 2; ++rp) {
                        const int r0 = q * 4 + rp * 2;
                        const int sl = m0 + mt * 32 + rp * 2 + 8 * q + 4 * k8;
                        const float res0 = (float)H_h[sl][c] + (float)H_l[sl][c];
                        const float res1 = (float)H_h[sl + 1][c] + (float)H_l[sl + 1][c];
                        const float y0 = fmaf(rs, res0, glu_val(accO[mt][r0],     accG[mt][r0],     sc_o, sh_o, sc_g, sh_g));
                        const float y1 = fmaf(rs, res1, glu_val(accO[mt][r0 + 1], accG[mt][r0 + 1], sc_o, sh_o, sc_g, sh_g));
                        half_t h0, l0, h1, l1;
                        split_pair(y0, y1, h0, l0, h1, l1);
                        H_h[sl][c] = h0; H_l[sl][c] = l0;
                        H_h[sl + 1][c] = h1; H_l[sl + 1][c] = l1;
                    }
        }
        __syncthreads();
    }

    // ---------------- L4 -> global outputs
#pragma unroll
    for (int i = 0; i < 2; ++i) { accO[i] = (floatx16)(0.f); accG[i] = (floatx16)(0.f); }
    layer_accum(H_h, H_l, Wh, Wl, w4_off, n32, k8, no, m0, half_id * 4, accO, accG);
    {
        const int c = no + n32;
        float sc_o, sh_o, sc_g, sh_g;
        bn_fold(bn4, b4, c, sc_o, sh_o);
        bn_fold(bn4, b4, c + 128, sc_g, sh_g);
        if (wq < 2) {
            if (wmode_last != 1) {
#pragma unroll
                for (int mt = 0; mt < 2; ++mt)
#pragma unroll
                    for (int reg = 0; reg < 16; ++reg) {
                        const int sl = m0 + mt * 32 + (reg & 3) + 8 * (reg >> 2) + 4 * k8;
                        const float res = (float)H_h[sl][c] + (float)H_l[sl][c];
                        const float y = fmaf(RES_SCALE_C, res, glu_val(accO[mt][reg], accG[mt][reg], sc_o, sh_o, sc_g, sh_g));
                        const float d = fmaxf(y, 0.f);
                        float* dp = ds + (size_t)(s0 + sl) * 64 + c;
                        *dp = (wmode_last == 2) ? d : (*dp + d);
                    }
            }
        } else {
#pragma unroll
            for (int mt = 0; mt < 2; ++mt)
#pragma unroll
                for (int q = 0; q < 4; ++q)
#pragma unroll
                    for (int rp = 0; rp < 2; ++rp) {
                        const int r0 = q * 4 + rp * 2;
                        const int sl = m0 + mt * 32 + rp * 2 + 8 * q + 4 * k8;
                        const float res0 = (float)H_h[sl][c] + (float)H_l[sl][c];
                        const float res1 = (float)H_h[sl + 1][c] + (float)H_l[sl + 1][c];
                        const float y0 = fmaf(RES_SCALE_C, res0, glu_val(accO[mt][r0],     accG[mt][r0],     sc_o, sh_o, sc_g, sh_g));
                        const float y1 = fmaf(RES_SCALE_C, res1, glu_val(accO[mt][r0 + 1], accG[mt][r0 + 1], sc_o, sh_o, sc_g, sh_g));
                        uint32_t w0, w1;
                        pack2_pair(y0, y1, w0, w1);
                        avp[(size_t)(s0 + sl) * 64 + (c - 64)] = w0;
                        avp[(size_t)(s0 + sl + 1) * 64 + (c - 64)] = w1;
                    }
        }
    }
}

// ---------------- final 64 -> 1 (RES_SCALE applied here: ds holds unscaled relu) ----------------
__global__ void final_kernel(const float* __restrict__ dsum, const float* __restrict__ out_W,
                             const float* __restrict__ out_b, float* __restrict__ out)
{
    const int s = blockIdx.x * 256 + threadIdx.x;
    float acc = 0.f;
    const float4* dp = (const float4*)(dsum + (size_t)s * 64);
    const float4* wp = (const float4*)out_W;
#pragma unroll
    for (int q = 0; q < 16; ++q) {
        const float4 d = dp[q];
        const float4 ww = wp[q];
        acc += d.x * ww.x + d.y * ww.y + d.z * ww.z + d.w * ww.w;
    }
    out[s] = fmaf(RES_SCALE_C, acc, out_b[0]);
}

// ---------------- launch ----------------
extern "C" void kernel_launch(void* const* d_in, const int* in_sizes, int n_in,
                              void* d_out, int out_size, void* d_ws, size_t ws_size,
                              hipStream_t stream)
{
    const float* x_num  = (const float*)d_in[0];
    const int*   x_cat  = (const int*)d_in[1];
    const float* emb_W  = (const float*)d_in[2];
    const float* in_bn  = (const float*)d_in[3];
    const float* sh_W0  = (const float*)d_in[4];
    const float* sh_b0  = (const float*)d_in[5];
    const float* sh_bn0 = (const float*)d_in[6];
    const float* sh_W1  = (const float*)d_in[7];
    const float* sh_b1  = (const float*)d_in[8];
    const float* sh_bn1 = (const float*)d_in[9];
    const float* init_W = (const float*)d_in[10];
    const float* init_b = (const float*)d_in[11];
    const float* init_bn= (const float*)d_in[12];
    const float* step_W = (const float*)d_in[13];
    const float* step_b = (const float*)d_in[14];
    const float* step_bn= (const float*)d_in[15];
    const float* att_W  = (const float*)d_in[16];
    const float* att_b  = (const float*)d_in[17];
    const float* att_bn = (const float*)d_in[18];
    const float* out_W  = (const float*)d_in[19];
    const float* out_b  = (const float*)d_in[20];

    const size_t B = B_TOT;
    char* p = (char*)d_ws;
    uint32_t* xp  = (uint32_t*)p;  p += B * 320 * 4;
    uint32_t* avp = (uint32_t*)p;  p += B * 64 * 4;
    half_t* Wh    = (half_t*)p;    p += 507904 * 2;
    half_t* Wl    = (half_t*)p;    p += 507904 * 2;
    half_t* aWh   = (half_t*)p;    p += 25600 * 2;
    half_t* aWl   = (half_t*)p;    p += 25600 * 2;
    float* pri    = (float*)p;     p += B * 80 * 4;
    float* ds     = (float*)p;     p += B * 64 * 4;

    wsplit_kernel<<<1984, 256, 0, stream>>>(sh_W0, sh_W1, init_W, step_W, Wh, Wl);
    wsplit_att_kernel<<<320, 80, 0, stream>>>(att_W, aWh, aWl);
    embed_bn_kernel<<<(B_TOT * 320) / 256, 256, 0, stream>>>(x_num, x_cat, emb_W, in_bn, xp);

    const int GB = B_TOT / 128;   // 512 blocks
    ft_chain<false><<<GB, 512, 0, stream>>>(xp, avp, Wh, Wl,
                                            nullptr, nullptr, nullptr, nullptr, nullptr,
                                            sh_b0, sh_bn0, sh_b1, sh_bn1,
                                            init_b, init_bn, init_b + 256, init_bn + 1024,
                                            (size_t)114688, (size_t)147456, ds, 1, 0);
    for (int st = 0; st < 5; ++st) {
        const size_t w3 = 180224 + (size_t)(st * 2 + 0) * 32768;
        const size_t w4 = 180224 + (size_t)(st * 2 + 1) * 32768;
        ft_chain<true><<<GB, 512, 0, stream>>>(xp, avp, Wh, Wl,
                                               aWh + st * 5120, aWl + st * 5120,
                                               att_b + st * 80, att_bn + st * 320, pri,
                                               sh_b0, sh_bn0, sh_b1, sh_bn1,
                                               step_b + (st * 2 + 0) * 256, step_bn + (st * 2 + 0) * 1024,
                                               step_b + (st * 2 + 1) * 256, step_bn + (st * 2 + 1) * 1024,
                                               w3, w4, ds, st == 0 ? 2 : 3, st);
    }
    final_kernel<<<B_TOT / 256, 256, 0, stream>>>(ds, out_W, out_b, (float*)d_out);
}

// Round 14
// 688.935 us; speedup vs baseline: 1.1325x; 1.0184x over previous
//
#include <hip/hip_runtime.h>
#include <math.h>
#include <stdint.h>

typedef _Float16 half_t;
typedef _Float16 half8 __attribute__((ext_vector_type(8)));
typedef __fp16 fp16x2 __attribute__((ext_vector_type(2)));
typedef float floatx4 __attribute__((ext_vector_type(4)));
typedef float floatx16 __attribute__((ext_vector_type(16)));

constexpr float BN_EPS_C = 1e-5f;
constexpr float RES_SCALE_C = 0.70710678118654752f;
constexpr float GAMMA_C = 1.5f;
#define B_TOT 65536

// ---------------- packed (hi,lo) fp16-pair helpers ----------------
__device__ __forceinline__ uint32_t pack2(float y) {
    const half_t h = (half_t)y;
    const half_t l = (half_t)(y - (float)h);
    union { half_t f; unsigned short u; } a, b; a.f = h; b.f = l;
    return (uint32_t)a.u | ((uint32_t)b.u << 16);
}
__device__ __forceinline__ void unpack2(uint32_t v, half_t& h, half_t& l) {
    union { unsigned short u; half_t f; } a, b;
    a.u = (unsigned short)(v & 0xffffu); b.u = (unsigned short)(v >> 16);
    h = a.f; l = b.f;
}
__device__ __forceinline__ void split_pair(float y0, float y1, half_t& h0, half_t& l0, half_t& h1, half_t& l1) {
    fp16x2 hh = __builtin_amdgcn_cvt_pkrtz(y0, y1);
    fp16x2 ll = __builtin_amdgcn_cvt_pkrtz(y0 - (float)hh.x, y1 - (float)hh.y);
    h0 = (half_t)hh.x; l0 = (half_t)ll.x; h1 = (half_t)hh.y; l1 = (half_t)ll.y;
}
__device__ __forceinline__ void pack2_pair(float y0, float y1, uint32_t& w0, uint32_t& w1) {
    fp16x2 hh = __builtin_amdgcn_cvt_pkrtz(y0, y1);
    fp16x2 ll = __builtin_amdgcn_cvt_pkrtz(y0 - (float)hh.x, y1 - (float)hh.y);
    const uint32_t hb = __builtin_bit_cast(uint32_t, hh);
    const uint32_t lb = __builtin_bit_cast(uint32_t, ll);
    w0 = (hb & 0xffffu) | (lb << 16);
    w1 = (hb >> 16) | (lb & 0xffff0000u);
}
__device__ __forceinline__ void unpack8(const uint32_t* wv, half8& h, half8& l) {
#pragma unroll
    for (int j = 0; j < 8; ++j) {
        half_t hh, ll; unpack2(wv[j], hh, ll);
        h[j] = hh; l[j] = ll;
    }
}

// ---------------- W split+repack (fragment-major, hi/lo planes) ----------------
// RES_SCALE folded into L3/L4 weights (their inputs are stored unscaled).
__global__ void wsplit_kernel(const float* __restrict__ sh_W0, const float* __restrict__ sh_W1,
                              const float* __restrict__ init_W, const float* __restrict__ step_W,
                              half_t* __restrict__ Wh, half_t* __restrict__ Wl)
{
    const int b = blockIdx.x, n = threadIdx.x;
    const float* src; int k; size_t base;
    if (b < 320)      { src = sh_W0;           k = b;       base = 0; }
    else if (b < 448) { src = sh_W1;           k = b - 320; base = 81920; }
    else if (b < 576) { src = init_W;          k = b - 448; base = 114688; }
    else if (b < 704) { src = init_W + 32768;  k = b - 576; base = 147456; }
    else {
        int j = (b - 704) >> 7; k = (b - 704) & 127;
        src = step_W + (size_t)j * 32768; base = 180224 + (size_t)j * 32768;
    }
    float v = src[k * 256 + n];
    if (b >= 448) v *= RES_SCALE_C;
    const half_t hi = (half_t)v;
    const half_t lo = (half_t)(v - (float)hi);
    const size_t idx = base + (size_t)(((k >> 3) * 256 + n) * 8 + (k & 7));
    Wh[idx] = hi; Wl[idx] = lo;
}

__global__ void wsplit_att_kernel(const float* __restrict__ att_W,
                                  half_t* __restrict__ aWh, half_t* __restrict__ aWl)
{
    const int b = blockIdx.x;
    const int n = threadIdx.x;
    const int step = b >> 6, k = b & 63;
    const float v = att_W[(size_t)b * 80 + n] * RES_SCALE_C;   // a is stored unscaled
    const half_t h = (half_t)v;
    const half_t l = (half_t)(v - (float)h);
    const size_t idx = (size_t)step * 5120 + (size_t)(((k >> 3) * 80 + n) * 8 + (k & 7));
    aWh[idx] = h; aWl[idx] = l;
}

__global__ void embed_bn_kernel(const float* __restrict__ x_num, const int* __restrict__ x_cat,
                                const float* __restrict__ emb_W, const float* __restrict__ in_bn,
                                uint32_t* __restrict__ xp)
{
    const int idx = blockIdx.x * 256 + threadIdx.x;
    const int s = idx / 320, j = idx - s * 320;
    float v;
    if (j < 64) v = x_num[(size_t)s * 64 + j];
    else {
        const int c = (j - 64) >> 4, e = (j - 64) & 15;
        v = emb_W[(size_t)(c * 1000 + x_cat[(size_t)s * 16 + c]) * 16 + e];
    }
    const float val = (v - in_bn[640 + j]) * (in_bn[j] * __frsqrt_rn(in_bn[960 + j] + BN_EPS_C)) + in_bn[320 + j];
    xp[idx] = pack2(val);
}

__device__ __forceinline__ void bn_fold(const float* __restrict__ bn, const float* __restrict__ bias,
                                        int c, float& sc, float& sh)
{
    sc = bn[c] * __frsqrt_rn(bn[768 + c] + BN_EPS_C);
    sh = fmaf(bias[c] - bn[512 + c], sc, bn[256 + c]);
}

__device__ __forceinline__ float glu_val(float accO, float accG,
                                         float sc_o, float sh_o, float sc_g, float sh_g)
{
    const float o = fmaf(accO, sc_o, sh_o);
    const float g = fmaf(accG, sc_g, sh_g);
    const float e = __expf(-g);
    return o * __builtin_amdgcn_rcpf(1.f + e);
}

#define MFMA32(A, B, C) C = __builtin_amdgcn_mfma_f32_32x32x16_f16(A, B, C, 0, 0, 0)
#define MFMA16(A, B, C) C = __builtin_amdgcn_mfma_f32_16x16x32_f16(A, B, C, 0, 0, 0)

// K=128 layer accumulate from split-plane H (8 slices of 16-k, rotated start); wave owns 2 m-tiles.
__device__ __forceinline__ void layer_accum(const half_t (*H_h)[136], const half_t (*H_l)[136],
                                            const half_t* __restrict__ Wh, const half_t* __restrict__ Wl,
                                            size_t off, int n32, int k8, int no, int m0, int rot,
                                            floatx16* accO, floatx16* accG)
{
#pragma unroll 2
    for (int s = 0; s < 8; ++s) {
        const int sl8 = (s + rot) & 7;
        const int kq = sl8 * 2 + k8;
        const size_t wo = off + (size_t)(kq * 256 + no + n32) * 8;
        const half8 bo_h = *(const half8*)(Wh + wo);
        const half8 bo_l = *(const half8*)(Wl + wo);
        const half8 bg_h = *(const half8*)(Wh + wo + 1024);
        const half8 bg_l = *(const half8*)(Wl + wo + 1024);
#pragma unroll
        for (int mt = 0; mt < 2; ++mt) {
            const half8 a_h = *(const half8*)&H_h[m0 + mt * 32 + n32][sl8 * 16 + k8 * 8];
            const half8 a_l = *(const half8*)&H_l[m0 + mt * 32 + n32][sl8 * 16 + k8 * 8];
            MFMA32(a_h, bo_h, accO[mt]); MFMA32(a_h, bg_h, accG[mt]);
            MFMA32(a_l, bo_h, accO[mt]); MFMA32(a_l, bg_h, accG[mt]);
            MFMA32(a_h, bo_l, accO[mt]); MFMA32(a_h, bg_l, accG[mt]);
        }
    }
}

// ---------------- fused (att+sparsemax) + FT chain, 128 samples/block, 512 threads / 8 waves ----------------
template<bool MASK>
__global__ __launch_bounds__(512, 4)
void ft_chain(const uint32_t* __restrict__ xp, uint32_t* __restrict__ avp,
              const half_t* __restrict__ Wh, const half_t* __restrict__ Wl,
              const half_t* __restrict__ aWh, const half_t* __restrict__ aWl,
              const float* __restrict__ att_b, const float* __restrict__ att_bn,
              float* __restrict__ prior,
              const float* __restrict__ b1, const float* __restrict__ bn1,
              const float* __restrict__ b2, const float* __restrict__ bn2,
              const float* __restrict__ b3, const float* __restrict__ bn3,
              const float* __restrict__ b4, const float* __restrict__ bn4,
              size_t w3_off, size_t w4_off,
              float* __restrict__ ds, int wmode_last, int step)
{
    // LDS overlay (79872 B):
    //  mgs float[128][84]           [0,43008)         live: att -> end of L1 staging
    //  As  uint32[2][128][36]       [43008,79872)     live: L1 (double-buffered chunk tiles)
    //  H   half planes [128][136]x2 [0,69632)         live: after L1 epilogue
    __shared__ __align__(16) char smem[79872];
    float    (*mgs)[84]  = (float    (*)[84])smem;
    uint32_t (*As0)[36]  = (uint32_t (*)[36])(smem + 43008);
    uint32_t (*As1)[36]  = (uint32_t (*)[36])(smem + 61440);
    half_t   (*H_h)[136] = (half_t   (*)[136])smem;
    half_t   (*H_l)[136] = (half_t   (*)[136])(smem + 34816);

    const int t = threadIdx.x;
    const int s0 = blockIdx.x * 128;
    const int w = t >> 6, lane = t & 63;
    const int wq = w & 3, wh = w >> 2;
    const int n32 = lane & 31, k8 = lane >> 5;
    const int quad = lane >> 4, l16 = lane & 15;
    const int no = 32 * wq;
    const int m0 = wh * 64;
    const int half_id = (blockIdx.x >> 8) & 1;
    const int rowA = t >> 2, kA8 = (t & 3) * 8;   // L1 staging: 8 words/thread/chunk

    if (MASK) {
        // z = BN(a@attW + b) * prior  (wave w owns m-tile w; avp read DIRECT from global)
        floatx4 zacc[5];
#pragma unroll
        for (int nt = 0; nt < 5; ++nt) zacc[nt] = (floatx4){0.f, 0.f, 0.f, 0.f};
        const uint32_t* aprow = avp + (size_t)(s0 + w * 16 + l16) * 64 + quad * 8;
#pragma unroll
        for (int kc = 0; kc < 64; kc += 32) {
            uint32_t wv[8];
            *(uint4*)&wv[0] = *(const uint4*)(aprow + kc);
            *(uint4*)&wv[4] = *(const uint4*)(aprow + kc + 4);
            half8 a_h, a_l;
            unpack8(wv, a_h, a_l);
            const int kq = (kc >> 3) + quad;
#pragma unroll
            for (int nt = 0; nt < 5; ++nt) {
                const size_t wi = (size_t)(kq * 80 + nt * 16 + l16) * 8;
                const half8 b_h = *(const half8*)(aWh + wi);
                const half8 b_l = *(const half8*)(aWl + wi);
                MFMA16(a_h, b_h, zacc[nt]);
                MFMA16(a_l, b_h, zacc[nt]);
                MFMA16(a_h, b_l, zacc[nt]);
            }
        }
        float preg[5][4];
#pragma unroll
        for (int nt = 0; nt < 5; ++nt) {
            const int c = nt * 16 + l16;
            const float sc = att_bn[c] * __frsqrt_rn(att_bn[240 + c] + BN_EPS_C);
            const float sh = fmaf(att_b[c] - att_bn[160 + c], sc, att_bn[80 + c]);
#pragma unroll
            for (int r = 0; r < 4; ++r) {
                const int sl = w * 16 + quad * 4 + r;
                const float pr = (step == 0) ? 1.f : prior[(size_t)(s0 + sl) * 80 + c];
                preg[nt][r] = pr;
                mgs[sl][c] = fmaf(zacc[nt][r], sc, sh) * pr;
            }
        }
        __syncthreads();
        // bisection sparsemax: 4 threads/sample, 20 groups each
        {
            const int samp = rowA, j0 = (t & 3) * 20;
            float zj[20], zmax = -1e30f;
#pragma unroll
            for (int j = 0; j < 20; ++j) { zj[j] = mgs[samp][j0 + j]; zmax = fmaxf(zmax, zj[j]); }
            zmax = fmaxf(zmax, __shfl_xor(zmax, 1));
            zmax = fmaxf(zmax, __shfl_xor(zmax, 2));
            float lo = zmax - 1.f, hi = zmax;
#pragma unroll 1
            for (int it = 0; it < 16; ++it) {
                const float mid = 0.5f * (lo + hi);
                float ssum = 0.f;
#pragma unroll
                for (int j = 0; j < 20; ++j) ssum += fmaxf(zj[j] - mid, 0.f);
                ssum += __shfl_xor(ssum, 1);
                ssum += __shfl_xor(ssum, 2);
                if (ssum >= 1.f) lo = mid; else hi = mid;
            }
            const float tau = 0.5f * (lo + hi);
#pragma unroll
            for (int j = 0; j < 20; ++j) mgs[samp][j0 + j] = fmaxf(zj[j] - tau, 0.f);
        }
        __syncthreads();
        // prior update
#pragma unroll
        for (int nt = 0; nt < 5; ++nt) {
            const int c = nt * 16 + l16;
#pragma unroll
            for (int r = 0; r < 4; ++r) {
                const int sl = w * 16 + quad * 4 + r;
                prior[(size_t)(s0 + sl) * 80 + c] = preg[nt][r] * (GAMMA_C - mgs[sl][c]);
            }
        }
    }

    // ---------------- L1: K=320 as 10 chunks of 32, double-buffered As, staging interleaved, fully unrolled
    floatx16 accO[2], accG[2];
#pragma unroll
    for (int i = 0; i < 2; ++i) { accO[i] = (floatx16)(0.f); accG[i] = (floatx16)(0.f); }

    const uint32_t* arow = xp + (size_t)(s0 + rowA) * 320 + kA8;
    uint32_t pfw[2][8];
    const int ic0 = half_id * 5;

    auto stage_half = [&](uint32_t (*Asb)[36], int c, int sl2, const uint32_t* pf) {
        const int kb = c * 32 + kA8 + sl2 * 4;   // 4 features
        uint4 out;
        if (MASK) {
            float m[4];
            if (c < 2) {
                const float4 mq = *(const float4*)&mgs[rowA][kb];
                m[0] = mq.x; m[1] = mq.y; m[2] = mq.z; m[3] = mq.w;
            } else {
                const float mg = mgs[rowA][64 + ((kb - 64) >> 4)];
                m[0] = m[1] = m[2] = m[3] = mg;
            }
            float y[4];
#pragma unroll
            for (int j = 0; j < 4; ++j) {
                half_t h, l; unpack2(pf[sl2 * 4 + j], h, l);
                y[j] = ((float)h + (float)l) * m[j];
            }
            uint32_t w0, w1, w2, w3;
            pack2_pair(y[0], y[1], w0, w1);
            pack2_pair(y[2], y[3], w2, w3);
            out = make_uint4(w0, w1, w2, w3);
        } else {
            out = *(const uint4*)&pf[sl2 * 4];
        }
        *(uint4*)&Asb[rowA][kA8 + sl2 * 4] = out;
    };

    // prologue
    {
        *(uint4*)&pfw[0][0] = *(const uint4*)(arow + ic0 * 32);
        *(uint4*)&pfw[0][4] = *(const uint4*)(arow + ic0 * 32 + 4);
        stage_half(As0, ic0, 0, pfw[0]);
        stage_half(As0, ic0, 1, pfw[0]);
        const int c1 = (ic0 + 1) % 10;
        *(uint4*)&pfw[1][0] = *(const uint4*)(arow + c1 * 32);
        *(uint4*)&pfw[1][4] = *(const uint4*)(arow + c1 * 32 + 4);
    }
    __syncthreads();

#pragma unroll
    for (int i = 0; i < 10; ++i) {
        const int cc = (ic0 + i) % 10;
        const int cn = (cc + 1 == 10) ? 0 : cc + 1;
        uint32_t (*AsC)[36] = (i & 1) ? As1 : As0;
        uint32_t (*AsN)[36] = (i & 1) ? As0 : As1;
        if (i <= 7) {
            const int c2 = (ic0 + i + 2) % 10;
            *(uint4*)&pfw[i & 1][0] = *(const uint4*)(arow + c2 * 32);
            *(uint4*)&pfw[i & 1][4] = *(const uint4*)(arow + c2 * 32 + 4);
        }
#pragma unroll
        for (int sl4 = 0; sl4 < 2; ++sl4) {
            if (i < 9) stage_half(AsN, cn, sl4, pfw[(i + 1) & 1]);
            const int kq = cc * 4 + sl4 * 2 + k8;
            const size_t wo = (size_t)(kq * 256 + no + n32) * 8;
            const half8 bo_h = *(const half8*)(Wh + wo);
            const half8 bo_l = *(const half8*)(Wl + wo);
            const half8 bg_h = *(const half8*)(Wh + wo + 1024);
            const half8 bg_l = *(const half8*)(Wl + wo + 1024);
#pragma unroll
            for (int mt = 0; mt < 2; ++mt) {
                uint32_t wv[8];
                *(uint4*)&wv[0] = *(const uint4*)&AsC[m0 + mt * 32 + n32][sl4 * 16 + k8 * 8];
                *(uint4*)&wv[4] = *(const uint4*)&AsC[m0 + mt * 32 + n32][sl4 * 16 + k8 * 8 + 4];
                half8 a_h, a_l;
                unpack8(wv, a_h, a_l);
                MFMA32(a_h, bo_h, accO[mt]); MFMA32(a_h, bg_h, accG[mt]);
                MFMA32(a_l, bo_h, accO[mt]); MFMA32(a_l, bg_h, accG[mt]);
                MFMA32(a_h, bo_l, accO[mt]); MFMA32(a_h, bg_l, accG[mt]);
            }
        }
        __syncthreads();
    }

    // L1 epilogue -> H planes + register-carried residual yres
    float yres[2][16];
    {
        const int c = no + n32;
        float sc_o, sh_o, sc_g, sh_g;
        bn_fold(bn1, b1, c, sc_o, sh_o);
        bn_fold(bn1, b1, c + 128, sc_g, sh_g);
#pragma unroll
        for (int mt = 0; mt < 2; ++mt)
#pragma unroll
            for (int q = 0; q < 4; ++q)
#pragma unroll
                for (int rp = 0; rp < 2; ++rp) {
                    const int r0 = q * 4 + rp * 2;
                    const int sl = m0 + mt * 32 + rp * 2 + 8 * q + 4 * k8;
                    const float y0 = glu_val(accO[mt][r0],     accG[mt][r0],     sc_o, sh_o, sc_g, sh_g);
                    const float y1 = glu_val(accO[mt][r0 + 1], accG[mt][r0 + 1], sc_o, sh_o, sc_g, sh_g);
                    yres[mt][r0] = y0; yres[mt][r0 + 1] = y1;
                    half_t h0, l0, h1, l1;
                    split_pair(y0, y1, h0, l0, h1, l1);
                    H_h[sl][c] = h0; H_l[sl][c] = l0;
                    H_h[sl + 1][c] = h1; H_l[sl + 1][c] = l1;
                }
    }
    __syncthreads();

    // ---------------- L2, L3 (residual from registers; scale folded)
#pragma unroll 1
    for (int layer = 0; layer < 2; ++layer) {
        const float* bb = layer ? b3 : b2;
        const float* bn = layer ? bn3 : bn2;
        const size_t off = layer ? w3_off : (size_t)81920;
        const float rs = layer ? RES_SCALE_C : 1.0f;
#pragma unroll
        for (int i = 0; i < 2; ++i) { accO[i] = (floatx16)(0.f); accG[i] = (floatx16)(0.f); }
        layer_accum(H_h, H_l, Wh, Wl, off, n32, k8, no, m0, half_id * 4, accO, accG);
        __syncthreads();
        {
            const int c = no + n32;
            float sc_o, sh_o, sc_g, sh_g;
            bn_fold(bn, bb, c, sc_o, sh_o);
            bn_fold(bn, bb, c + 128, sc_g, sh_g);
#pragma unroll
            for (int mt = 0; mt < 2; ++mt)
#pragma unroll
                for (int q = 0; q < 4; ++q)
#pragma unroll
                    for (int rp = 0; rp < 2; ++rp) {
                        const int r0 = q * 4 + rp * 2;
                        const int sl = m0 + mt * 32 + rp * 2 + 8 * q + 4 * k8;
                        const float y0 = fmaf(rs, yres[mt][r0],     glu_val(accO[mt][r0],     accG[mt][r0],     sc_o, sh_o, sc_g, sh_g));
                        const float y1 = fmaf(rs, yres[mt][r0 + 1], glu_val(accO[mt][r0 + 1], accG[mt][r0 + 1], sc_o, sh_o, sc_g, sh_g));
                        yres[mt][r0] = y0; yres[mt][r0 + 1] = y1;
                        half_t h0, l0, h1, l1;
                        split_pair(y0, y1, h0, l0, h1, l1);
                        H_h[sl][c] = h0; H_l[sl][c] = l0;
                        H_h[sl + 1][c] = h1; H_l[sl + 1][c] = l1;
                    }
        }
        __syncthreads();
    }

    // ---------------- L4 -> global outputs (residual from registers)
#pragma unroll
    for (int i = 0; i < 2; ++i) { accO[i] = (floatx16)(0.f); accG[i] = (floatx16)(0.f); }
    layer_accum(H_h, H_l, Wh, Wl, w4_off, n32, k8, no, m0, half_id * 4, accO, accG);
    {
        const int c = no + n32;
        float sc_o, sh_o, sc_g, sh_g;
        bn_fold(bn4, b4, c, sc_o, sh_o);
        bn_fold(bn4, b4, c + 128, sc_g, sh_g);
        if (wq < 2) {
            if (wmode_last != 1) {
#pragma unroll
                for (int mt = 0; mt < 2; ++mt)
#pragma unroll
                    for (int q = 0; q < 4; ++q)
#pragma unroll
                        for (int rp = 0; rp < 2; ++rp) {
                            const int r0 = q * 4 + rp * 2;
                            const int sl = m0 + mt * 32 + rp * 2 + 8 * q + 4 * k8;
                            const float y0 = fmaf(RES_SCALE_C, yres[mt][r0],     glu_val(accO[mt][r0],     accG[mt][r0],     sc_o, sh_o, sc_g, sh_g));
                            const float y1 = fmaf(RES_SCALE_C, yres[mt][r0 + 1], glu_val(accO[mt][r0 + 1], accG[mt][r0 + 1], sc_o, sh_o, sc_g, sh_g));
                            const float d0 = fmaxf(y0, 0.f);
                            const float d1 = fmaxf(y1, 0.f);
                            float* dp0 = ds + (size_t)(s0 + sl) * 64 + c;
                            float* dp1 = ds + (size_t)(s0 + sl + 1) * 64 + c;
                            if (wmode_last == 2) { *dp0 = d0; *dp1 = d1; }
                            else { *dp0 += d0; *dp1 += d1; }
                        }
            }
        } else {
#pragma unroll
            for (int mt = 0; mt < 2; ++mt)
#pragma unroll
                for (int q = 0; q < 4; ++q)
#pragma unroll
                    for (int rp = 0; rp < 2; ++rp) {
                        const int r0 = q * 4 + rp * 2;
                        const int sl = m0 + mt * 32 + rp * 2 + 8 * q + 4 * k8;
                        const float y0 = fmaf(RES_SCALE_C, yres[mt][r0],     glu_val(accO[mt][r0],     accG[mt][r0],     sc_o, sh_o, sc_g, sh_g));
                        const float y1 = fmaf(RES_SCALE_C, yres[mt][r0 + 1], glu_val(accO[mt][r0 + 1], accG[mt][r0 + 1], sc_o, sh_o, sc_g, sh_g));
                        uint32_t w0, w1;
                        pack2_pair(y0, y1, w0, w1);
                        avp[(size_t)(s0 + sl) * 64 + (c - 64)] = w0;
                        avp[(size_t)(s0 + sl + 1) * 64 + (c - 64)] = w1;
                    }
        }
    }
}

// ---------------- final 64 -> 1 (RES_SCALE applied here: ds holds unscaled relu) ----------------
__global__ void final_kernel(const float* __restrict__ dsum, const float* __restrict__ out_W,
                             const float* __restrict__ out_b, float* __restrict__ out)
{
    const int s = blockIdx.x * 256 + threadIdx.x;
    float acc = 0.f;
    const float4* dp = (const float4*)(dsum + (size_t)s * 64);
    const float4* wp = (const float4*)out_W;
#pragma unroll
    for (int q = 0; q < 16; ++q) {
        const float4 d = dp[q];
        const float4 ww = wp[q];
        acc += d.x * ww.x + d.y * ww.y + d.z * ww.z + d.w * ww.w;
    }
    out[s] = fmaf(RES_SCALE_C, acc, out_b[0]);
}

// ---------------- launch ----------------
extern "C" void kernel_launch(void* const* d_in, const int* in_sizes, int n_in,
                              void* d_out, int out_size, void* d_ws, size_t ws_size,
                              hipStream_t stream)
{
    const float* x_num  = (const float*)d_in[0];
    const int*   x_cat  = (const int*)d_in[1];
    const float* emb_W  = (const float*)d_in[2];
    const float* in_bn  = (const float*)d_in[3];
    const float* sh_W0  = (const float*)d_in[4];
    const float* sh_b0  = (const float*)d_in[5];
    const float* sh_bn0 = (const float*)d_in[6];
    const float* sh_W1  = (const float*)d_in[7];
    const float* sh_b1  = (const float*)d_in[8];
    const float* sh_bn1 = (const float*)d_in[9];
    const float* init_W = (const float*)d_in[10];
    const float* init_b = (const float*)d_in[11];
    const float* init_bn= (const float*)d_in[12];
    const float* step_W = (const float*)d_in[13];
    const float* step_b = (const float*)d_in[14];
    const float* step_bn= (const float*)d_in[15];
    const float* att_W  = (const float*)d_in[16];
    const float* att_b  = (const float*)d_in[17];
    const float* att_bn = (const float*)d_in[18];
    const float* out_W  = (const float*)d_in[19];
    const float* out_b  = (const float*)d_in[20];

    const size_t B = B_TOT;
    char* p = (char*)d_ws;
    uint32_t* xp  = (uint32_t*)p;  p += B * 320 * 4;
    uint32_t* avp = (uint32_t*)p;  p += B * 64 * 4;
    half_t* Wh    = (half_t*)p;    p += 507904 * 2;
    half_t* Wl    = (half_t*)p;    p += 507904 * 2;
    half_t* aWh   = (half_t*)p;    p += 25600 * 2;
    half_t* aWl   = (half_t*)p;    p += 25600 * 2;
    float* pri    = (float*)p;     p += B * 80 * 4;
    float* ds     = (float*)p;     p += B * 64 * 4;

    wsplit_kernel<<<1984, 256, 0, stream>>>(sh_W0, sh_W1, init_W, step_W, Wh, Wl);
    wsplit_att_kernel<<<320, 80, 0, stream>>>(att_W, aWh, aWl);
    embed_bn_kernel<<<(B_TOT * 320) / 256, 256, 0, stream>>>(x_num, x_cat, emb_W, in_bn, xp);

    const int GB = B_TOT / 128;   // 512 blocks
    ft_chain<false><<<GB, 512, 0, stream>>>(xp, avp, Wh, Wl,
                                            nullptr, nullptr, nullptr, nullptr, nullptr,
                                            sh_b0, sh_bn0, sh_b1, sh_bn1,
                                            init_b, init_bn, init_b + 256, init_bn + 1024,
                                            (size_t)114688, (size_t)147456, ds, 1, 0);
    for (int st = 0; st < 5; ++st) {
        const size_t w3 = 180224 + (size_t)(st * 2 + 0) * 32768;
        const size_t w4 = 180224 + (size_t)(st * 2 + 1) * 32768;
        ft_chain<true><<<GB, 512, 0, stream>>>(xp, avp, Wh, Wl,
                                               aWh + st * 5120, aWl + st * 5120,
                                               att_b + st * 80, att_bn + st * 320, pri,
                                               sh_b0, sh_bn0, sh_b1, sh_bn1,
                                               step_b + (st * 2 + 0) * 256, step_bn + (st * 2 + 0) * 1024,
                                               step_b + (st * 2 + 1) * 256, step_bn + (st * 2 + 1) * 1024,
                                               w3, w4, ds, st == 0 ? 2 : 3, st);
    }
    final_kernel<<<B_TOT / 256, 256, 0, stream>>>(ds, out_W, out_b, (float*)d_out);
}

// Round 15
// 663.572 us; speedup vs baseline: 1.1758x; 1.0382x over previous
//
#include <hip/hip_runtime.h>
#include <math.h>
#include <stdint.h>

typedef _Float16 half_t;
typedef _Float16 half8 __attribute__((ext_vector_type(8)));
typedef __fp16 fp16x2 __attribute__((ext_vector_type(2)));
typedef float floatx4 __attribute__((ext_vector_type(4)));
typedef float floatx16 __attribute__((ext_vector_type(16)));

constexpr float BN_EPS_C = 1e-5f;
constexpr float RES_SCALE_C = 0.70710678118654752f;
constexpr float GAMMA_C = 1.5f;
#define B_TOT 65536

// ---------------- fp16-pair helpers ----------------
__device__ __forceinline__ void unpack2(uint32_t v, half_t& h, half_t& l) {
    union { unsigned short u; half_t f; } a, b;
    a.u = (unsigned short)(v & 0xffffu); b.u = (unsigned short)(v >> 16);
    h = a.f; l = b.f;
}
__device__ __forceinline__ void split_pair(float y0, float y1, half_t& h0, half_t& l0, half_t& h1, half_t& l1) {
    fp16x2 hh = __builtin_amdgcn_cvt_pkrtz(y0, y1);
    fp16x2 ll = __builtin_amdgcn_cvt_pkrtz(y0 - (float)hh.x, y1 - (float)hh.y);
    h0 = (half_t)hh.x; l0 = (half_t)ll.x; h1 = (half_t)hh.y; l1 = (half_t)ll.y;
}
__device__ __forceinline__ void pack2_pair(float y0, float y1, uint32_t& w0, uint32_t& w1) {
    fp16x2 hh = __builtin_amdgcn_cvt_pkrtz(y0, y1);
    fp16x2 ll = __builtin_amdgcn_cvt_pkrtz(y0 - (float)hh.x, y1 - (float)hh.y);
    const uint32_t hb = __builtin_bit_cast(uint32_t, hh);
    const uint32_t lb = __builtin_bit_cast(uint32_t, ll);
    w0 = (hb & 0xffffu) | (lb << 16);
    w1 = (hb >> 16) | (lb & 0xffff0000u);
}
__device__ __forceinline__ void unpack8(const uint32_t* wv, half8& h, half8& l) {
#pragma unroll
    for (int j = 0; j < 8; ++j) {
        half_t hh, ll; unpack2(wv[j], hh, ll);
        h[j] = hh; l[j] = ll;
    }
}

// ---------------- W split+repack (fragment-major, hi/lo planes) ----------------
// RES_SCALE folded into L3/L4 weights (their inputs are stored unscaled).
__global__ void wsplit_kernel(const float* __restrict__ sh_W0, const float* __restrict__ sh_W1,
                              const float* __restrict__ init_W, const float* __restrict__ step_W,
                              half_t* __restrict__ Wh, half_t* __restrict__ Wl)
{
    const int b = blockIdx.x, n = threadIdx.x;
    const float* src; int k; size_t base;
    if (b < 320)      { src = sh_W0;           k = b;       base = 0; }
    else if (b < 448) { src = sh_W1;           k = b - 320; base = 81920; }
    else if (b < 576) { src = init_W;          k = b - 448; base = 114688; }
    else if (b < 704) { src = init_W + 32768;  k = b - 576; base = 147456; }
    else {
        int j = (b - 704) >> 7; k = (b - 704) & 127;
        src = step_W + (size_t)j * 32768; base = 180224 + (size_t)j * 32768;
    }
    float v = src[k * 256 + n];
    if (b >= 448) v *= RES_SCALE_C;
    const half_t hi = (half_t)v;
    const half_t lo = (half_t)(v - (float)hi);
    const size_t idx = base + (size_t)(((k >> 3) * 256 + n) * 8 + (k & 7));
    Wh[idx] = hi; Wl[idx] = lo;
}

__global__ void wsplit_att_kernel(const float* __restrict__ att_W,
                                  half_t* __restrict__ aWh, half_t* __restrict__ aWl)
{
    const int b = blockIdx.x;
    const int n = threadIdx.x;
    const int step = b >> 6, k = b & 63;
    const float v = att_W[(size_t)b * 80 + n] * RES_SCALE_C;   // a is stored unscaled
    const half_t h = (half_t)v;
    const half_t l = (half_t)(v - (float)h);
    const size_t idx = (size_t)step * 5120 + (size_t)(((k >> 3) * 80 + n) * 8 + (k & 7));
    aWh[idx] = h; aWl[idx] = l;
}

// ---------------- folded BN tables: bnf[layer][0..255]=sc, [256..511]=sh (bias folded) ----------------
__global__ void bnfold_kernel(const float* __restrict__ sh_bn0, const float* __restrict__ sh_b0,
                              const float* __restrict__ sh_bn1, const float* __restrict__ sh_b1,
                              const float* __restrict__ init_bn, const float* __restrict__ init_b,
                              const float* __restrict__ step_bn, const float* __restrict__ step_b,
                              float* __restrict__ bnf)
{
    const int layer = blockIdx.x, ch = threadIdx.x;
    const float *bn, *bi;
    if (layer == 0)      { bn = sh_bn0; bi = sh_b0; }
    else if (layer == 1) { bn = sh_bn1; bi = sh_b1; }
    else if (layer == 2) { bn = init_bn; bi = init_b; }
    else if (layer == 3) { bn = init_bn + 1024; bi = init_b + 256; }
    else                 { bn = step_bn + (layer - 4) * 1024; bi = step_b + (layer - 4) * 256; }
    const float sc = bn[ch] * __frsqrt_rn(bn[768 + ch] + BN_EPS_C);
    const float sh = fmaf(bi[ch] - bn[512 + ch], sc, bn[256 + ch]);
    bnf[layer * 512 + ch] = sc;
    bnf[layer * 512 + 256 + ch] = sh;
}

// ---------------- embed + input BN -> split half planes ----------------
__global__ void embed_bn_kernel(const float* __restrict__ x_num, const int* __restrict__ x_cat,
                                const float* __restrict__ emb_W, const float* __restrict__ in_bn,
                                half_t* __restrict__ xh, half_t* __restrict__ xl)
{
    const int idx = blockIdx.x * 256 + threadIdx.x;
    const int s = idx / 320, j = idx - s * 320;
    float v;
    if (j < 64) v = x_num[(size_t)s * 64 + j];
    else {
        const int c = (j - 64) >> 4, e = (j - 64) & 15;
        v = emb_W[(size_t)(c * 1000 + x_cat[(size_t)s * 16 + c]) * 16 + e];
    }
    const float val = (v - in_bn[640 + j]) * (in_bn[j] * __frsqrt_rn(in_bn[960 + j] + BN_EPS_C)) + in_bn[320 + j];
    const half_t h = (half_t)val;
    xh[idx] = h;
    xl[idx] = (half_t)(val - (float)h);
}

__device__ __forceinline__ float glu_val(float accO, float accG,
                                         float sc_o, float sh_o, float sc_g, float sh_g)
{
    const float o = fmaf(accO, sc_o, sh_o);
    const float g = fmaf(accG, sc_g, sh_g);
    const float e = __expf(-g);
    return o * __builtin_amdgcn_rcpf(1.f + e);
}

#define MFMA32(A, B, C) C = __builtin_amdgcn_mfma_f32_32x32x16_f16(A, B, C, 0, 0, 0)
#define MFMA16(A, B, C) C = __builtin_amdgcn_mfma_f32_16x16x32_f16(A, B, C, 0, 0, 0)

// K=128 layer accumulate from split-plane H (8 slices of 16-k, rotated start); wave owns 2 m-tiles.
__device__ __forceinline__ void layer_accum(const half_t (*H_h)[136], const half_t (*H_l)[136],
                                            const half_t* __restrict__ Wh, const half_t* __restrict__ Wl,
                                            size_t off, int n32, int k8, int no, int m0, int rot,
                                            floatx16* accO, floatx16* accG)
{
#pragma unroll 2
    for (int s = 0; s < 8; ++s) {
        const int sl8 = (s + rot) & 7;
        const int kq = sl8 * 2 + k8;
        const size_t wo = off + (size_t)(kq * 256 + no + n32) * 8;
        const half8 bo_h = *(const half8*)(Wh + wo);
        const half8 bo_l = *(const half8*)(Wl + wo);
        const half8 bg_h = *(const half8*)(Wh + wo + 1024);
        const half8 bg_l = *(const half8*)(Wl + wo + 1024);
#pragma unroll
        for (int mt = 0; mt < 2; ++mt) {
            const half8 a_h = *(const half8*)&H_h[m0 + mt * 32 + n32][sl8 * 16 + k8 * 8];
            const half8 a_l = *(const half8*)&H_l[m0 + mt * 32 + n32][sl8 * 16 + k8 * 8];
            MFMA32(a_h, bo_h, accO[mt]); MFMA32(a_h, bg_h, accG[mt]);
            MFMA32(a_l, bo_h, accO[mt]); MFMA32(a_l, bg_h, accG[mt]);
            MFMA32(a_h, bo_l, accO[mt]); MFMA32(a_h, bg_l, accG[mt]);
        }
    }
}

// ---------------- fused (att+sparsemax) + FT chain, 128 samples/block, 512 threads / 8 waves ----------------
template<bool MASK>
__global__ __launch_bounds__(512, 4)
void ft_chain(const half_t* __restrict__ xh, const half_t* __restrict__ xl,
              uint32_t* __restrict__ avp,
              const half_t* __restrict__ Wh, const half_t* __restrict__ Wl,
              const half_t* __restrict__ aWh, const half_t* __restrict__ aWl,
              const float* __restrict__ att_b, const float* __restrict__ att_bn,
              float* __restrict__ prior,
              const float* __restrict__ bnf1, const float* __restrict__ bnf2,
              const float* __restrict__ bnf3, const float* __restrict__ bnf4,
              size_t w3_off, size_t w4_off,
              float* __restrict__ ds, int wmode_last, int step)
{
    // LDS overlay (81920 B = exactly 2 blocks x 160KiB/CU):
    //  mgs float[128][80]                [0,40960)   live: att -> end of L1 staging
    //  As split planes 2bufs x h/l x [128][40]h:
    //    Ash0 @40960  Asl0 @51200  Ash1 @61440  Asl1 @71680   (each 10240 B)
    //  H planes [128][136]h x2 @0/@34816 (69632 B) live after L1 epilogue
    __shared__ __align__(16) char smem[81920];
    float  (*mgs)[80]   = (float  (*)[80])smem;
    half_t (*Ash0)[40]  = (half_t (*)[40])(smem + 40960);
    half_t (*Asl0)[40]  = (half_t (*)[40])(smem + 51200);
    half_t (*Ash1)[40]  = (half_t (*)[40])(smem + 61440);
    half_t (*Asl1)[40]  = (half_t (*)[40])(smem + 71680);
    half_t (*H_h)[136]  = (half_t (*)[136])smem;
    half_t (*H_l)[136]  = (half_t (*)[136])(smem + 34816);

    const int t = threadIdx.x;
    const int s0 = blockIdx.x * 128;
    const int w = t >> 6, lane = t & 63;
    const int wq = w & 3, wh = w >> 2;
    const int n32 = lane & 31, k8 = lane >> 5;
    const int quad = lane >> 4, l16 = lane & 15;
    const int no = 32 * wq;
    const int m0 = wh * 64;
    const int half_id = (blockIdx.x >> 8) & 1;
    const int rowA = t >> 2, kA8 = (t & 3) * 8;   // L1 staging: 8 features/thread/chunk

    if (MASK) {
        // z = BN(a@attW + b) * prior  (wave w owns m-tile w; avp read direct from global)
        floatx4 zacc[5];
#pragma unroll
        for (int nt = 0; nt < 5; ++nt) zacc[nt] = (floatx4){0.f, 0.f, 0.f, 0.f};
        const uint32_t* aprow = avp + (size_t)(s0 + w * 16 + l16) * 64 + quad * 8;
#pragma unroll
        for (int kc = 0; kc < 64; kc += 32) {
            uint32_t wv[8];
            *(uint4*)&wv[0] = *(const uint4*)(aprow + kc);
            *(uint4*)&wv[4] = *(const uint4*)(aprow + kc + 4);
            half8 a_h, a_l;
            unpack8(wv, a_h, a_l);
            const int kq = (kc >> 3) + quad;
#pragma unroll
            for (int nt = 0; nt < 5; ++nt) {
                const size_t wi = (size_t)(kq * 80 + nt * 16 + l16) * 8;
                const half8 b_h = *(const half8*)(aWh + wi);
                const half8 b_l = *(const half8*)(aWl + wi);
                MFMA16(a_h, b_h, zacc[nt]);
                MFMA16(a_l, b_h, zacc[nt]);
                MFMA16(a_h, b_l, zacc[nt]);
            }
        }
        float preg[5][4];
#pragma unroll
        for (int nt = 0; nt < 5; ++nt) {
            const int c = nt * 16 + l16;
            const float sc = att_bn[c] * __frsqrt_rn(att_bn[240 + c] + BN_EPS_C);
            const float sh = fmaf(att_b[c] - att_bn[160 + c], sc, att_bn[80 + c]);
#pragma unroll
            for (int r = 0; r < 4; ++r) {
                const int sl = w * 16 + quad * 4 + r;
                const float pr = (step == 0) ? 1.f : prior[(size_t)(s0 + sl) * 80 + c];
                preg[nt][r] = pr;
                mgs[sl][c] = fmaf(zacc[nt][r], sc, sh) * pr;
            }
        }
        __syncthreads();
        // bisection sparsemax: 4 threads/sample, 20 groups each
        {
            const int samp = rowA, j0 = (t & 3) * 20;
            float zj[20], zmax = -1e30f;
#pragma unroll
            for (int j = 0; j < 20; ++j) { zj[j] = mgs[samp][j0 + j]; zmax = fmaxf(zmax, zj[j]); }
            zmax = fmaxf(zmax, __shfl_xor(zmax, 1));
            zmax = fmaxf(zmax, __shfl_xor(zmax, 2));
            float lo = zmax - 1.f, hi = zmax;
#pragma unroll 1
            for (int it = 0; it < 16; ++it) {
                const float mid = 0.5f * (lo + hi);
                float ssum = 0.f;
#pragma unroll
                for (int j = 0; j < 20; ++j) ssum += fmaxf(zj[j] - mid, 0.f);
                ssum += __shfl_xor(ssum, 1);
                ssum += __shfl_xor(ssum, 2);
                if (ssum >= 1.f) lo = mid; else hi = mid;
            }
            const float tau = 0.5f * (lo + hi);
#pragma unroll
            for (int j = 0; j < 20; ++j) mgs[samp][j0 + j] = fmaxf(zj[j] - tau, 0.f);
        }
        __syncthreads();
        // prior update
#pragma unroll
        for (int nt = 0; nt < 5; ++nt) {
            const int c = nt * 16 + l16;
#pragma unroll
            for (int r = 0; r < 4; ++r) {
                const int sl = w * 16 + quad * 4 + r;
                prior[(size_t)(s0 + sl) * 80 + c] = preg[nt][r] * (GAMMA_C - mgs[sl][c]);
            }
        }
    }

    // ---------------- L1: K=320 as 10 chunks of 32, double-buffered split-plane As, fully unrolled
    floatx16 accO[2], accG[2];
#pragma unroll
    for (int i = 0; i < 2; ++i) { accO[i] = (floatx16)(0.f); accG[i] = (floatx16)(0.f); }

    const half_t* xrh = xh + (size_t)(s0 + rowA) * 320 + kA8;
    const half_t* xrl = xl + (size_t)(s0 + rowA) * 320 + kA8;
    half8 pfh[2], pfl[2];
    const int ic0 = half_id * 5;

    auto stage_chunk = [&](half_t (*Ah)[40], half_t (*Al)[40], int c, const half8& ph, const half8& pl) {
        half8 hh, ll;
        if (MASK) {
            const int kb = c * 32 + kA8;
            float y[8];
            if (c < 2) {
                const float4 m0q = *(const float4*)&mgs[rowA][kb];
                const float4 m1q = *(const float4*)&mgs[rowA][kb + 4];
                const float mm[8] = {m0q.x, m0q.y, m0q.z, m0q.w, m1q.x, m1q.y, m1q.z, m1q.w};
#pragma unroll
                for (int j = 0; j < 8; ++j) y[j] = ((float)ph[j] + (float)pl[j]) * mm[j];
            } else {
                const float mg = mgs[rowA][64 + ((kb - 64) >> 4)];
#pragma unroll
                for (int j = 0; j < 8; ++j) y[j] = ((float)ph[j] + (float)pl[j]) * mg;
            }
#pragma unroll
            for (int j = 0; j < 8; j += 2) {
                half_t h0, l0, h1, l1;
                split_pair(y[j], y[j + 1], h0, l0, h1, l1);
                hh[j] = h0; hh[j + 1] = h1; ll[j] = l0; ll[j + 1] = l1;
            }
        } else {
            hh = ph; ll = pl;
        }
        *(half8*)&Ah[rowA][kA8] = hh;
        *(half8*)&Al[rowA][kA8] = ll;
    };

    // prologue: load c0, stage into buf0, load c1
    {
        pfh[0] = *(const half8*)(xrh + ic0 * 32);
        pfl[0] = *(const half8*)(xrl + ic0 * 32);
        stage_chunk(Ash0, Asl0, ic0, pfh[0], pfl[0]);
        const int c1 = (ic0 + 1) % 10;
        pfh[1] = *(const half8*)(xrh + c1 * 32);
        pfl[1] = *(const half8*)(xrl + c1 * 32);
    }
    __syncthreads();

#pragma unroll
    for (int i = 0; i < 10; ++i) {
        const int cc = (ic0 + i) % 10;
        const int cn = (cc + 1 == 10) ? 0 : cc + 1;
        half_t (*AhC)[40] = (i & 1) ? Ash1 : Ash0;
        half_t (*AlC)[40] = (i & 1) ? Asl1 : Asl0;
        half_t (*AhN)[40] = (i & 1) ? Ash0 : Ash1;
        half_t (*AlN)[40] = (i & 1) ? Asl0 : Asl1;
        if (i <= 7) {   // prefetch chunk i+2 into slot i&1 (consumed at iter i+1's staging)
            const int c2 = (ic0 + i + 2) % 10;
            pfh[i & 1] = *(const half8*)(xrh + c2 * 32);
            pfl[i & 1] = *(const half8*)(xrl + c2 * 32);
        }
        if (i < 9) stage_chunk(AhN, AlN, cn, pfh[(i + 1) & 1], pfl[(i + 1) & 1]);
#pragma unroll
        for (int sl4 = 0; sl4 < 2; ++sl4) {
            const int kq = cc * 4 + sl4 * 2 + k8;
            const size_t wo = (size_t)(kq * 256 + no + n32) * 8;
            const half8 bo_h = *(const half8*)(Wh + wo);
            const half8 bo_l = *(const half8*)(Wl + wo);
            const half8 bg_h = *(const half8*)(Wh + wo + 1024);
            const half8 bg_l = *(const half8*)(Wl + wo + 1024);
#pragma unroll
            for (int mt = 0; mt < 2; ++mt) {
                const half8 a_h = *(const half8*)&AhC[m0 + mt * 32 + n32][sl4 * 16 + k8 * 8];
                const half8 a_l = *(const half8*)&AlC[m0 + mt * 32 + n32][sl4 * 16 + k8 * 8];
                MFMA32(a_h, bo_h, accO[mt]); MFMA32(a_h, bg_h, accG[mt]);
                MFMA32(a_l, bo_h, accO[mt]); MFMA32(a_l, bg_h, accG[mt]);
                MFMA32(a_h, bo_l, accO[mt]); MFMA32(a_h, bg_l, accG[mt]);
            }
        }
        __syncthreads();
    }

    // L1 epilogue -> H planes + register-carried residual yres
    float yres[2][16];
    {
        const int c = no + n32;
        const float sc_o = bnf1[c],       sh_o = bnf1[256 + c];
        const float sc_g = bnf1[c + 128], sh_g = bnf1[384 + c];
#pragma unroll
        for (int mt = 0; mt < 2; ++mt)
#pragma unroll
            for (int q = 0; q < 4; ++q)
#pragma unroll
                for (int rp = 0; rp < 2; ++rp) {
                    const int r0 = q * 4 + rp * 2;
                    const int sl = m0 + mt * 32 + rp * 2 + 8 * q + 4 * k8;
                    const float y0 = glu_val(accO[mt][r0],     accG[mt][r0],     sc_o, sh_o, sc_g, sh_g);
                    const float y1 = glu_val(accO[mt][r0 + 1], accG[mt][r0 + 1], sc_o, sh_o, sc_g, sh_g);
                    yres[mt][r0] = y0; yres[mt][r0 + 1] = y1;
                    half_t h0, l0, h1, l1;
                    split_pair(y0, y1, h0, l0, h1, l1);
                    H_h[sl][c] = h0; H_l[sl][c] = l0;
                    H_h[sl + 1][c] = h1; H_l[sl + 1][c] = l1;
                }
    }
    __syncthreads();

    // ---------------- L2, L3 (residual from registers; scale folded)
#pragma unroll 1
    for (int layer = 0; layer < 2; ++layer) {
        const float* bf = layer ? bnf3 : bnf2;
        const size_t off = layer ? w3_off : (size_t)81920;
        const float rs = layer ? RES_SCALE_C : 1.0f;
#pragma unroll
        for (int i = 0; i < 2; ++i) { accO[i] = (floatx16)(0.f); accG[i] = (floatx16)(0.f); }
        layer_accum(H_h, H_l, Wh, Wl, off, n32, k8, no, m0, half_id * 4, accO, accG);
        __syncthreads();
        {
            const int c = no + n32;
            const float sc_o = bf[c],       sh_o = bf[256 + c];
            const float sc_g = bf[c + 128], sh_g = bf[384 + c];
#pragma unroll
            for (int mt = 0; mt < 2; ++mt)
#pragma unroll
                for (int q = 0; q < 4; ++q)
#pragma unroll
                    for (int rp = 0; rp < 2; ++rp) {
                        const int r0 = q * 4 + rp * 2;
                        const int sl = m0 + mt * 32 + rp * 2 + 8 * q + 4 * k8;
                        const float y0 = fmaf(rs, yres[mt][r0],     glu_val(accO[mt][r0],     accG[mt][r0],     sc_o, sh_o, sc_g, sh_g));
                        const float y1 = fmaf(rs, yres[mt][r0 + 1], glu_val(accO[mt][r0 + 1], accG[mt][r0 + 1], sc_o, sh_o, sc_g, sh_g));
                        yres[mt][r0] = y0; yres[mt][r0 + 1] = y1;
                        half_t h0, l0, h1, l1;
                        split_pair(y0, y1, h0, l0, h1, l1);
                        H_h[sl][c] = h0; H_l[sl][c] = l0;
                        H_h[sl + 1][c] = h1; H_l[sl + 1][c] = l1;
                    }
        }
        __syncthreads();
    }

    // ---------------- L4 -> global outputs (residual from registers)
#pragma unroll
    for (int i = 0; i < 2; ++i) { accO[i] = (floatx16)(0.f); accG[i] = (floatx16)(0.f); }
    layer_accum(H_h, H_l, Wh, Wl, w4_off, n32, k8, no, m0, half_id * 4, accO, accG);
    {
        const int c = no + n32;
        const float sc_o = bnf4[c],       sh_o = bnf4[256 + c];
        const float sc_g = bnf4[c + 128], sh_g = bnf4[384 + c];
        if (wq < 2) {
            if (wmode_last != 1) {
#pragma unroll
                for (int mt = 0; mt < 2; ++mt)
#pragma unroll
                    for (int q = 0; q < 4; ++q)
#pragma unroll
                        for (int rp = 0; rp < 2; ++rp) {
                            const int r0 = q * 4 + rp * 2;
                            const int sl = m0 + mt * 32 + rp * 2 + 8 * q + 4 * k8;
                            const float y0 = fmaf(RES_SCALE_C, yres[mt][r0],     glu_val(accO[mt][r0],     accG[mt][r0],     sc_o, sh_o, sc_g, sh_g));
                            const float y1 = fmaf(RES_SCALE_C, yres[mt][r0 + 1], glu_val(accO[mt][r0 + 1], accG[mt][r0 + 1], sc_o, sh_o, sc_g, sh_g));
                            const float d0 = fmaxf(y0, 0.f);
                            const float d1 = fmaxf(y1, 0.f);
                            float* dp0 = ds + (size_t)(s0 + sl) * 64 + c;
                            float* dp1 = ds + (size_t)(s0 + sl + 1) * 64 + c;
                            if (wmode_last == 2) { *dp0 = d0; *dp1 = d1; }
                            else { *dp0 += d0; *dp1 += d1; }
                        }
            }
        } else {
#pragma unroll
            for (int mt = 0; mt < 2; ++mt)
#pragma unroll
                for (int q = 0; q < 4; ++q)
#pragma unroll
                    for (int rp = 0; rp < 2; ++rp) {
                        const int r0 = q * 4 + rp * 2;
                        const int sl = m0 + mt * 32 + rp * 2 + 8 * q + 4 * k8;
                        const float y0 = fmaf(RES_SCALE_C, yres[mt][r0],     glu_val(accO[mt][r0],     accG[mt][r0],     sc_o, sh_o, sc_g, sh_g));
                        const float y1 = fmaf(RES_SCALE_C, yres[mt][r0 + 1], glu_val(accO[mt][r0 + 1], accG[mt][r0 + 1], sc_o, sh_o, sc_g, sh_g));
                        uint32_t w0, w1;
                        pack2_pair(y0, y1, w0, w1);
                        avp[(size_t)(s0 + sl) * 64 + (c - 64)] = w0;
                        avp[(size_t)(s0 + sl + 1) * 64 + (c - 64)] = w1;
                    }
        }
    }
}

// ---------------- final 64 -> 1 (RES_SCALE applied here: ds holds unscaled relu) ----------------
__global__ void final_kernel(const float* __restrict__ dsum, const float* __restrict__ out_W,
                             const float* __restrict__ out_b, float* __restrict__ out)
{
    const int s = blockIdx.x * 256 + threadIdx.x;
    float acc = 0.f;
    const float4* dp = (const float4*)(dsum + (size_t)s * 64);
    const float4* wp = (const float4*)out_W;
#pragma unroll
    for (int q = 0; q < 16; ++q) {
        const float4 d = dp[q];
        const float4 ww = wp[q];
        acc += d.x * ww.x + d.y * ww.y + d.z * ww.z + d.w * ww.w;
    }
    out[s] = fmaf(RES_SCALE_C, acc, out_b[0]);
}

// ---------------- launch ----------------
extern "C" void kernel_launch(void* const* d_in, const int* in_sizes, int n_in,
                              void* d_out, int out_size, void* d_ws, size_t ws_size,
                              hipStream_t stream)
{
    const float* x_num  = (const float*)d_in[0];
    const int*   x_cat  = (const int*)d_in[1];
    const float* emb_W  = (const float*)d_in[2];
    const float* in_bn  = (const float*)d_in[3];
    const float* sh_W0  = (const float*)d_in[4];
    const float* sh_b0  = (const float*)d_in[5];
    const float* sh_bn0 = (const float*)d_in[6];
    const float* sh_W1  = (const float*)d_in[7];
    const float* sh_b1  = (const float*)d_in[8];
    const float* sh_bn1 = (const float*)d_in[9];
    const float* init_W = (const float*)d_in[10];
    const float* init_b = (const float*)d_in[11];
    const float* init_bn= (const float*)d_in[12];
    const float* step_W = (const float*)d_in[13];
    const float* step_b = (const float*)d_in[14];
    const float* step_bn= (const float*)d_in[15];
    const float* att_W  = (const float*)d_in[16];
    const float* att_b  = (const float*)d_in[17];
    const float* att_bn = (const float*)d_in[18];
    const float* out_W  = (const float*)d_in[19];
    const float* out_b  = (const float*)d_in[20];

    const size_t B = B_TOT;
    char* p = (char*)d_ws;
    half_t* xh    = (half_t*)p;    p += B * 320 * 2;
    half_t* xl    = (half_t*)p;    p += B * 320 * 2;
    uint32_t* avp = (uint32_t*)p;  p += B * 64 * 4;
    half_t* Wh    = (half_t*)p;    p += 507904 * 2;
    half_t* Wl    = (half_t*)p;    p += 507904 * 2;
    half_t* aWh   = (half_t*)p;    p += 25600 * 2;
    half_t* aWl   = (half_t*)p;    p += 25600 * 2;
    float* pri    = (float*)p;     p += B * 80 * 4;
    float* ds     = (float*)p;     p += B * 64 * 4;
    float* bnf    = (float*)p;     p += 14 * 512 * 4;

    wsplit_kernel<<<1984, 256, 0, stream>>>(sh_W0, sh_W1, init_W, step_W, Wh, Wl);
    wsplit_att_kernel<<<320, 80, 0, stream>>>(att_W, aWh, aWl);
    bnfold_kernel<<<14, 256, 0, stream>>>(sh_bn0, sh_b0, sh_bn1, sh_b1, init_bn, init_b, step_bn, step_b, bnf);
    embed_bn_kernel<<<(B_TOT * 320) / 256, 256, 0, stream>>>(x_num, x_cat, emb_W, in_bn, xh, xl);

    const int GB = B_TOT / 128;   // 512 blocks
    ft_chain<false><<<GB, 512, 0, stream>>>(xh, xl, avp, Wh, Wl,
                                            nullptr, nullptr, nullptr, nullptr, nullptr,
                                            bnf, bnf + 512, bnf + 1024, bnf + 1536,
                                            (size_t)114688, (size_t)147456, ds, 1, 0);
    for (int st = 0; st < 5; ++st) {
        const size_t w3 = 180224 + (size_t)(st * 2 + 0) * 32768;
        const size_t w4 = 180224 + (size_t)(st * 2 + 1) * 32768;
        ft_chain<true><<<GB, 512, 0, stream>>>(xh, xl, avp, Wh, Wl,
                                               aWh + st * 5120, aWl + st * 5120,
                                               att_b + st * 80, att_bn + st * 320, pri,
                                               bnf, bnf + 512,
                                               bnf + (4 + 2 * st) * 512, bnf + (5 + 2 * st) * 512,
                                               w3, w4, ds, st == 0 ? 2 : 3, st);
    }
    final_kernel<<<B_TOT / 256, 256, 0, stream>>>(ds, out_W, out_b, (float*)d_out);
}